// Round 2
// baseline (764.163 us; speedup 1.0000x reference)
//
#include <hip/hip_runtime.h>

typedef unsigned short u16;
typedef short bf16x8 __attribute__((ext_vector_type(8)));
typedef float f32x4 __attribute__((ext_vector_type(4)));
typedef u16 u16x4 __attribute__((ext_vector_type(4)));

#define DEVFN static __device__ __forceinline__

constexpr int Bz = 2, Nn = 2048, Mm = 512, Cc = 1536, Hh = 12, HD = 128;
constexpr int Ss = Nn + Mm;                 // 2560
constexpr float EPSV = 1e-6f;
constexpr float SCL = 0.08838834764831845f; // 128^-0.5

DEVFN u16 f2bf(float f) {
  union { float f; unsigned u; } v; v.f = f;
  unsigned r = v.u + 0x7fffu + ((v.u >> 16) & 1u);
  return (u16)(r >> 16);
}

DEVFN void gload16(const void* g, void* l) {
  __builtin_amdgcn_global_load_lds((const __attribute__((address_space(1))) void*)g,
                                   (__attribute__((address_space(3))) void*)l, 16, 0, 0);
}

DEVFN f32x4 mfma16(bf16x8 a, bf16x8 b, f32x4 c) {
  return __builtin_amdgcn_mfma_f32_16x16x32_bf16(a, b, c, 0, 0, 0);
}

// ---------------- prep kernels ----------------

__global__ void k_convert(const float* __restrict__ in, u16* __restrict__ out, int n) {
  int i = (blockIdx.x * blockDim.x + threadIdx.x) * 4;
  if (i < n) {
    float4 v = *(const float4*)(in + i);
    u16x4 o = { f2bf(v.x), f2bf(v.y), f2bf(v.z), f2bf(v.w) };
    *(u16x4*)(out + i) = o;
  }
}

// in: f32 (R x Ccols) row-major -> out: bf16 (Ccols x R)
__global__ void k_transpose_conv(const float* __restrict__ in, u16* __restrict__ out,
                                 int R, int Ccols) {
  __shared__ float t[32][33];
  int c0 = blockIdx.x * 32, r0 = blockIdx.y * 32;
  int lr = threadIdx.x >> 5, lc = threadIdx.x & 31;
#pragma unroll
  for (int i = 0; i < 4; ++i)
    t[lr + 8 * i][lc] = in[(long)(r0 + lr + 8 * i) * Ccols + c0 + lc];
  __syncthreads();
#pragma unroll
  for (int i = 0; i < 4; ++i)
    out[(long)(c0 + lr + 8 * i) * R + r0 + lc] = f2bf(t[lc][lr + 8 * i]);
}

// v (BH, Ss, HD) bf16 -> vt (BH, HD, Ss)
__global__ void k_transpose_v(const u16* __restrict__ in, u16* __restrict__ out) {
  __shared__ u16 t[32][33];
  int bh = blockIdx.z;
  const u16* ib = in + (long)bh * Ss * HD;
  u16* ob = out + (long)bh * HD * Ss;
  int s0 = blockIdx.x * 32, d0 = blockIdx.y * 32;
  int lr = threadIdx.x >> 5, lc = threadIdx.x & 31;
#pragma unroll
  for (int i = 0; i < 4; ++i)
    t[lr + 8 * i][lc] = ib[(long)(s0 + lr + 8 * i) * HD + d0 + lc];
  __syncthreads();
#pragma unroll
  for (int i = 0; i < 4; ++i)
    ob[(long)(d0 + lr + 8 * i) * Ss + s0 + lc] = t[lc][lr + 8 * i];
}

__global__ void k_bias(const float* __restrict__ w, float* __restrict__ bias) {
  int i = blockIdx.x * 256 + threadIdx.x;
  if (i < Bz * Ss) {
    int b = i / Ss, s = i % Ss;
    bias[i] = (s < Nn) ? 0.0f : logf(fmaxf(w[b * Mm + s - Nn], 1e-4f));
  }
}

// ---------------- GEMM (A row-major MxK bf16, Bt = B^T (N x K) bf16) ----------------
// MODE 0: plain + bproj -> f32 out
// MODE 1: qkv epilogue  (s=0 q: RMS+RoPE, s=1 kx: RMS+RoPE, s=2 vx)
// MODE 2: kv  epilogue  (s=0 ky: RMS only -> k[N..], s=1 vy -> v[N..])
template <int MODE>
__global__ __launch_bounds__(256, 2) void k_gemm(
    const u16* __restrict__ A, const u16* __restrict__ Bt,
    int K, int NC, int rowsPerB,
    const float* __restrict__ pos, const float* __restrict__ qnw,
    const float* __restrict__ knw, const float* __restrict__ bprj,
    u16* __restrict__ qout, u16* __restrict__ kout, u16* __restrict__ vout,
    float* __restrict__ fout) {
  __shared__ __align__(16) u16 As[128 * 32];
  __shared__ __align__(16) u16 Bs[128 * 32];
  __shared__ float red[256];
  const int tid = threadIdx.x;
  const int lane = tid & 63;
  const int wid = tid >> 6;
  const int g = lane >> 4, cl = lane & 15;
  const int wr = wid >> 1, wc = wid & 1;
  const long m0 = (long)blockIdx.x * 128, n0 = (long)blockIdx.y * 128;

  f32x4 acc[4][4] = {};

  const int trA = tid >> 2;
  const int db = (tid & 3) ^ (trA & 3);           // source 16B-block (swizzle inverse)
  const char* Ab = (const char*)A + (m0 + trA) * (long)K * 2 + db * 16;
  const char* Bb = (const char*)Bt + (n0 + trA) * (long)K * 2 + db * 16;
  const long rstep = (long)64 * K * 2;
  char* dstA0 = (char*)As + ((tid & ~63) << 4);
  char* dstB0 = (char*)Bs + ((tid & ~63) << 4);

  for (int kt = 0; kt < K / 32; ++kt) {
    __syncthreads();
    gload16(Ab + kt * 64, dstA0);
    gload16(Ab + kt * 64 + rstep, dstA0 + 4096);
    gload16(Bb + kt * 64, dstB0);
    gload16(Bb + kt * 64 + rstep, dstB0 + 4096);
    __syncthreads();
    bf16x8 af[4], bfr[4];
#pragma unroll
    for (int m = 0; m < 4; ++m) {
      int row = wr * 64 + m * 16 + cl;
      af[m] = *(const bf16x8*)((const char*)As + row * 64 + ((g ^ (row & 3)) << 4));
    }
#pragma unroll
    for (int n = 0; n < 4; ++n) {
      int row = wc * 64 + n * 16 + cl;
      bfr[n] = *(const bf16x8*)((const char*)Bs + row * 64 + ((g ^ (row & 3)) << 4));
    }
#pragma unroll
    for (int m = 0; m < 4; ++m)
#pragma unroll
      for (int n = 0; n < 4; ++n)
        acc[m][n] = mfma16(af[m], bfr[n], acc[m][n]);
  }

  if (MODE == 0) {
#pragma unroll
    for (int n = 0; n < 4; ++n) {
      int col = (int)n0 + wc * 64 + n * 16 + cl;
      float bv = bprj[col];
#pragma unroll
      for (int m = 0; m < 4; ++m)
#pragma unroll
        for (int r = 0; r < 4; ++r) {
          long row = m0 + wr * 64 + m * 16 + 4 * g + r;
          fout[row * NC + col] = acc[m][n][r] + bv;
        }
    }
    return;
  }

  // ---- fused RMS / RoPE epilogue ----
  const int ct = blockIdx.y;
  const int s_idx = ct / Hh, h = ct % Hh;
  const int bb = (int)(m0 / rowsPerB);
  const int bh = bb * Hh + h;
  const int seq0 = (int)(m0 % rowsPerB) + wr * 64;
  const bool do_norm = (MODE == 1) ? (s_idx < 2) : (s_idx == 0);
  const bool do_rope = (MODE == 1) && (s_idx < 2);

  if (do_norm) {
    float rs[4][4];
#pragma unroll
    for (int m = 0; m < 4; ++m)
#pragma unroll
      for (int r = 0; r < 4; ++r) {
        float t = 0.f;
#pragma unroll
        for (int n = 0; n < 4; ++n) t += acc[m][n][r] * acc[m][n][r];
        t += __shfl_xor(t, 1);
        t += __shfl_xor(t, 2);
        t += __shfl_xor(t, 4);
        t += __shfl_xor(t, 8);
        if (cl == 0) red[wc * 128 + wr * 64 + m * 16 + 4 * g + r] = t;
      }
    __syncthreads();
#pragma unroll
    for (int m = 0; m < 4; ++m)
#pragma unroll
      for (int r = 0; r < 4; ++r) {
        int row = wr * 64 + m * 16 + 4 * g + r;
        rs[m][r] = rsqrtf((red[row] + red[128 + row]) * (1.0f / 128.0f) + EPSV);
      }
    const float* nw = (MODE == 1 && s_idx == 0) ? qnw : knw;
#pragma unroll
    for (int n = 0; n < 4; ++n) {
      float nwv = nw[wc * 64 + n * 16 + cl];
#pragma unroll
      for (int m = 0; m < 4; ++m)
#pragma unroll
        for (int r = 0; r < 4; ++r) acc[m][n][r] *= rs[m][r] * nwv;
    }
  }

  if (do_rope && wc == 0) {
#pragma unroll
    for (int m = 0; m < 4; ++m)
#pragma unroll
      for (int r = 0; r < 4; ++r) {
        int seq = seq0 + m * 16 + 4 * g + r;
#pragma unroll
        for (int n = 0; n < 2; ++n) {
          int d = n * 16 + cl;  // 0..31
          float cs = pos[(seq * 32 + d) * 2 + 0];
          float sn = pos[(seq * 32 + d) * 2 + 1];
          float t1 = acc[m][n][r], t2 = acc[m][n + 2][r];
          acc[m][n][r] = t1 * cs - t2 * sn;
          acc[m][n + 2][r] = t1 * sn + t2 * cs;
        }
      }
  }

  u16* ob;
  long sbase;
  if (MODE == 1) {
    if (s_idx == 0) { ob = qout; sbase = (long)bh * Nn; }
    else if (s_idx == 1) { ob = kout; sbase = (long)bh * Ss; }
    else { ob = vout; sbase = (long)bh * Ss; }
  } else {
    ob = (s_idx == 0) ? kout : vout;
    sbase = (long)bh * Ss + Nn;
  }
#pragma unroll
  for (int m = 0; m < 4; ++m)
#pragma unroll
    for (int r = 0; r < 4; ++r) {
      long rowb = (sbase + seq0 + m * 16 + 4 * g + r) * HD;
#pragma unroll
      for (int n = 0; n < 4; ++n)
        ob[rowb + wc * 64 + n * 16 + cl] = f2bf(acc[m][n][r]);
    }
}

// ---------------- flash attention (register-resident, no staging) ----------------
// Q (BH,Nn,HD) bf16, K (BH,Ss,HD) bf16, Vt (BH,HD,Ss) bf16, bias (Bz,Ss) f32
// out: (B,N,C) bf16.  64 q-rows/block, 16 per wave; K/V read global->reg (L1/L2-resident).
constexpr int PSTR = 72;  // P-buffer row stride (u16), pads bank groups

__global__ __launch_bounds__(256, 3) void k_flash(
    const u16* __restrict__ Q, const u16* __restrict__ K, const u16* __restrict__ Vt,
    const float* __restrict__ bias, u16* __restrict__ Aout) {
  __shared__ __align__(16) u16 Ps[4][16 * PSTR];
  const int tid = threadIdx.x;
  const int lane = tid & 63;
  const int wid = tid >> 6;
  const int g = lane >> 4, cl = lane & 15;
  const int bh = blockIdx.y, b = bh / Hh, h = bh % Hh;
  const int n0 = blockIdx.x * 64;

  const u16* Qg = Q + ((long)bh * Nn + n0 + wid * 16) * HD;
  const u16* Kg = K + (long)bh * Ss * HD;
  const u16* Vg = Vt + (long)bh * HD * Ss;
  const float* bg = bias + b * Ss;

  // Q fragments straight from global: lane holds row=cl, d = kk*32 + g*8 .. +8
  bf16x8 qf[4];
#pragma unroll
  for (int kk = 0; kk < 4; ++kk)
    qf[kk] = *(const bf16x8*)(Qg + cl * HD + kk * 32 + g * 8);

  f32x4 ov[8] = {};
  float mi[4], li[4];
#pragma unroll
  for (int r = 0; r < 4; ++r) { mi[r] = -3.0e38f; li[r] = 0.f; }

  u16* pp = Ps[wid];

  for (int t = 0; t < Ss / 64; ++t) {
    const int kv0 = t * 64;
    // S = Q K^T  (per lane: q = wid*16 + 4g + r, kv = n*16 + cl)
    f32x4 sc[4] = {};
#pragma unroll
    for (int n = 0; n < 4; ++n) {
      const u16* kr = Kg + (long)(kv0 + n * 16 + cl) * HD + g * 8;
#pragma unroll
      for (int kk = 0; kk < 4; ++kk) {
        bf16x8 kf = *(const bf16x8*)(kr + kk * 32);
        sc[n] = mfma16(qf[kk], kf, sc[n]);
      }
    }
    float bv[4];
#pragma unroll
    for (int n = 0; n < 4; ++n) bv[n] = bg[kv0 + n * 16 + cl];
    float corr[4];
#pragma unroll
    for (int r = 0; r < 4; ++r) {
      float mx = -3.0e38f;
#pragma unroll
      for (int n = 0; n < 4; ++n) {
        float s = sc[n][r] * SCL + bv[n];
        sc[n][r] = s;
        mx = fmaxf(mx, s);
      }
      mx = fmaxf(mx, __shfl_xor(mx, 1));
      mx = fmaxf(mx, __shfl_xor(mx, 2));
      mx = fmaxf(mx, __shfl_xor(mx, 4));
      mx = fmaxf(mx, __shfl_xor(mx, 8));
      float mnew = fmaxf(mi[r], mx);
      float co = __expf(mi[r] - mnew);
      mi[r] = mnew;
      float rsum = 0.f;
#pragma unroll
      for (int n = 0; n < 4; ++n) {
        float p = __expf(sc[n][r] - mnew);
        sc[n][r] = p;
        rsum += p;
      }
      rsum += __shfl_xor(rsum, 1);
      rsum += __shfl_xor(rsum, 2);
      rsum += __shfl_xor(rsum, 4);
      rsum += __shfl_xor(rsum, 8);
      li[r] = li[r] * co + rsum;
      corr[r] = co;
    }
#pragma unroll
    for (int nd = 0; nd < 8; ++nd)
#pragma unroll
      for (int r = 0; r < 4; ++r) ov[nd][r] *= corr[r];

    // P (f32) -> bf16 via per-wave LDS transpose (no barriers: wave-private)
#pragma unroll
    for (int n = 0; n < 4; ++n)
#pragma unroll
      for (int r = 0; r < 4; ++r) {
        int prow = 4 * g + r, col = n * 16 + cl;
        pp[prow * PSTR + (((col >> 3) ^ (prow & 7)) << 3) + (col & 7)] = f2bf(sc[n][r]);
      }
    bf16x8 pf[2];
#pragma unroll
    for (int ks = 0; ks < 2; ++ks)
      pf[ks] = *(const bf16x8*)((const char*)pp + cl * (PSTR * 2) +
                                (((ks * 4 + g) ^ (cl & 7)) << 4));
    // O += P V   (vf: lane holds d-row = nd*16 + cl, kv = ks*32 + g*8 .. +8)
#pragma unroll
    for (int nd = 0; nd < 8; ++nd) {
      const u16* vr = Vg + (long)(nd * 16 + cl) * Ss + kv0 + g * 8;
#pragma unroll
      for (int ks = 0; ks < 2; ++ks) {
        bf16x8 vf = *(const bf16x8*)(vr + ks * 32);
        ov[nd] = mfma16(pf[ks], vf, ov[nd]);
      }
    }
  }

#pragma unroll
  for (int r = 0; r < 4; ++r) {
    float inv = 1.0f / li[r];
    long row = (long)b * Nn + n0 + wid * 16 + 4 * g + r;
    long base = row * Cc + h * HD;
#pragma unroll
    for (int nd = 0; nd < 8; ++nd)
      Aout[base + nd * 16 + cl] = f2bf(ov[nd][r] * inv);
  }
}

// ---------------- launcher ----------------

extern "C" void kernel_launch(void* const* d_in, const int* in_sizes, int n_in,
                              void* d_out, int out_size, void* d_ws, size_t ws_size,
                              hipStream_t stream) {
  const float* x = (const float*)d_in[0];
  const float* y = (const float*)d_in[1];
  const float* pos = (const float*)d_in[2];
  const float* ytw = (const float*)d_in[3];
  const float* Wqkv = (const float*)d_in[4];
  const float* Wkv = (const float*)d_in[5];
  const float* qnw = (const float*)d_in[6];
  const float* knw = (const float*)d_in[7];
  const float* Wproj = (const float*)d_in[8];
  const float* bproj = (const float*)d_in[9];
  float* out = (float*)d_out;
  char* ws = (char*)d_ws;

  size_t o = 0;
  auto take = [&](size_t b) {
    char* p = ws + o;
    o += (b + 255) & ~(size_t)255;
    return p;
  };
  u16* xb = (u16*)take((size_t)Bz * Nn * Cc * 2);
  u16* yb = (u16*)take((size_t)Bz * Mm * Cc * 2);
  u16* wqkvt = (u16*)take((size_t)3 * Cc * Cc * 2);
  u16* wkvt = (u16*)take((size_t)2 * Cc * Cc * 2);
  u16* wprjt = (u16*)take((size_t)Cc * Cc * 2);
  u16* qb = (u16*)take((size_t)Bz * Hh * Nn * HD * 2);
  u16* kb = (u16*)take((size_t)Bz * Hh * Ss * HD * 2);
  u16* vb = (u16*)take((size_t)Bz * Hh * Ss * HD * 2);
  u16* vtb = (u16*)take((size_t)Bz * Hh * Ss * HD * 2);
  u16* ab = (u16*)take((size_t)Bz * Nn * Cc * 2);
  float* bias = (float*)take((size_t)Bz * Ss * 4);

  k_convert<<<dim3(Bz * Nn * Cc / 1024), 256, 0, stream>>>(x, xb, Bz * Nn * Cc);
  k_convert<<<dim3(Bz * Mm * Cc / 1024), 256, 0, stream>>>(y, yb, Bz * Mm * Cc);
  k_transpose_conv<<<dim3(3 * Cc / 32, Cc / 32), 256, 0, stream>>>(Wqkv, wqkvt, Cc, 3 * Cc);
  k_transpose_conv<<<dim3(2 * Cc / 32, Cc / 32), 256, 0, stream>>>(Wkv, wkvt, Cc, 2 * Cc);
  k_transpose_conv<<<dim3(Cc / 32, Cc / 32), 256, 0, stream>>>(Wproj, wprjt, Cc, Cc);
  k_bias<<<dim3((Bz * Ss + 255) / 256), 256, 0, stream>>>(ytw, bias);
  k_gemm<1><<<dim3(Bz * Nn / 128, 3 * Cc / 128), 256, 0, stream>>>(
      xb, wqkvt, Cc, 3 * Cc, Nn, pos, qnw, knw, nullptr, qb, kb, vb, nullptr);
  k_gemm<2><<<dim3(Bz * Mm / 128, 2 * Cc / 128), 256, 0, stream>>>(
      yb, wkvt, Cc, 2 * Cc, Mm, pos, qnw, knw, nullptr, nullptr, kb, vb, nullptr);
  k_transpose_v<<<dim3(Ss / 32, HD / 32, Bz * Hh), 256, 0, stream>>>(vb, vtb);
  k_flash<<<dim3(Nn / 64, Bz * Hh), 256, 0, stream>>>(qb, kb, vtb, bias, ab);
  k_gemm<0><<<dim3(Bz * Nn / 128, Cc / 128), 256, 0, stream>>>(
      ab, wprjt, Cc, Cc, Nn, nullptr, nullptr, nullptr, bproj, nullptr, nullptr, nullptr, out);
}

// Round 3
// 427.381 us; speedup vs baseline: 1.7880x; 1.7880x over previous
//
#include <hip/hip_runtime.h>

typedef unsigned short u16;
typedef short bf16x8 __attribute__((ext_vector_type(8)));
typedef float f32x4 __attribute__((ext_vector_type(4)));
typedef u16 u16x4 __attribute__((ext_vector_type(4)));

#define DEVFN static __device__ __forceinline__

constexpr int Bz = 2, Nn = 2048, Mm = 512, Cc = 1536, Hh = 12, HD = 128;
constexpr int Ss = Nn + Mm;                 // 2560
constexpr float EPSV = 1e-6f;
constexpr float SCL = 0.08838834764831845f; // 128^-0.5

DEVFN u16 f2bf(float f) {
  union { float f; unsigned u; } v; v.f = f;
  unsigned r = v.u + 0x7fffu + ((v.u >> 16) & 1u);
  return (u16)(r >> 16);
}

DEVFN unsigned cvtpk(float lo, float hi) {
  unsigned r;
  asm("v_cvt_pk_bf16_f32 %0, %1, %2" : "=v"(r) : "v"(lo), "v"(hi));
  return r;
}

DEVFN void gload16(const void* g, void* l) {
  __builtin_amdgcn_global_load_lds((const __attribute__((address_space(1))) void*)g,
                                   (__attribute__((address_space(3))) void*)l, 16, 0, 0);
}

DEVFN f32x4 mfma16(bf16x8 a, bf16x8 b, f32x4 c) {
  return __builtin_amdgcn_mfma_f32_16x16x32_bf16(a, b, c, 0, 0, 0);
}

// ---------------- prep kernels ----------------

__global__ void k_convert(const float* __restrict__ in, u16* __restrict__ out, int n) {
  int i = (blockIdx.x * blockDim.x + threadIdx.x) * 4;
  if (i < n) {
    float4 v = *(const float4*)(in + i);
    u16x4 o = { f2bf(v.x), f2bf(v.y), f2bf(v.z), f2bf(v.w) };
    *(u16x4*)(out + i) = o;
  }
}

// in: f32 (R x Ccols) row-major -> out: bf16 (Ccols x R)
__global__ void k_transpose_conv(const float* __restrict__ in, u16* __restrict__ out,
                                 int R, int Ccols) {
  __shared__ float t[32][33];
  int c0 = blockIdx.x * 32, r0 = blockIdx.y * 32;
  int lr = threadIdx.x >> 5, lc = threadIdx.x & 31;
#pragma unroll
  for (int i = 0; i < 4; ++i)
    t[lr + 8 * i][lc] = in[(long)(r0 + lr + 8 * i) * Ccols + c0 + lc];
  __syncthreads();
#pragma unroll
  for (int i = 0; i < 4; ++i)
    out[(long)(c0 + lr + 8 * i) * R + r0 + lc] = f2bf(t[lc][lr + 8 * i]);
}

// v (BH, Ss, HD) bf16 -> vt (BH, HD, Ss)
__global__ void k_transpose_v(const u16* __restrict__ in, u16* __restrict__ out) {
  __shared__ u16 t[32][33];
  int bh = blockIdx.z;
  const u16* ib = in + (long)bh * Ss * HD;
  u16* ob = out + (long)bh * HD * Ss;
  int s0 = blockIdx.x * 32, d0 = blockIdx.y * 32;
  int lr = threadIdx.x >> 5, lc = threadIdx.x & 31;
#pragma unroll
  for (int i = 0; i < 4; ++i)
    t[lr + 8 * i][lc] = ib[(long)(s0 + lr + 8 * i) * HD + d0 + lc];
  __syncthreads();
#pragma unroll
  for (int i = 0; i < 4; ++i)
    ob[(long)(d0 + lr + 8 * i) * Ss + s0 + lc] = t[lc][lr + 8 * i];
}

__global__ void k_bias(const float* __restrict__ w, float* __restrict__ bias) {
  int i = blockIdx.x * 256 + threadIdx.x;
  if (i < Bz * Ss) {
    int b = i / Ss, s = i % Ss;
    bias[i] = (s < Nn) ? 0.0f : logf(fmaxf(w[b * Mm + s - Nn], 1e-4f));
  }
}

// ---------------- GEMM (A row-major MxK bf16, Bt = B^T (N x K) bf16) ----------------
// MODE 0: plain + bproj -> f32 out
// MODE 1: qkv epilogue  (s=0 q: RMS+RoPE+SCL, s=1 kx: RMS+RoPE, s=2 vx)
// MODE 2: kv  epilogue  (s=0 ky: RMS only -> k[N..], s=1 vy -> v[N..])
template <int MODE>
__global__ __launch_bounds__(256, 2) void k_gemm(
    const u16* __restrict__ A, const u16* __restrict__ Bt,
    int K, int NC, int rowsPerB,
    const float* __restrict__ pos, const float* __restrict__ qnw,
    const float* __restrict__ knw, const float* __restrict__ bprj,
    u16* __restrict__ qout, u16* __restrict__ kout, u16* __restrict__ vout,
    float* __restrict__ fout) {
  __shared__ __align__(16) u16 As[128 * 32];
  __shared__ __align__(16) u16 Bs[128 * 32];
  __shared__ float red[256];
  const int tid = threadIdx.x;
  const int lane = tid & 63;
  const int wid = tid >> 6;
  const int g = lane >> 4, cl = lane & 15;
  const int wr = wid >> 1, wc = wid & 1;
  const long m0 = (long)blockIdx.x * 128, n0 = (long)blockIdx.y * 128;

  f32x4 acc[4][4] = {};

  const int trA = tid >> 2;
  const int db = (tid & 3) ^ (trA & 3);           // source 16B-block (swizzle inverse)
  const char* Ab = (const char*)A + (m0 + trA) * (long)K * 2 + db * 16;
  const char* Bb = (const char*)Bt + (n0 + trA) * (long)K * 2 + db * 16;
  const long rstep = (long)64 * K * 2;
  char* dstA0 = (char*)As + ((tid & ~63) << 4);
  char* dstB0 = (char*)Bs + ((tid & ~63) << 4);

  for (int kt = 0; kt < K / 32; ++kt) {
    __syncthreads();
    gload16(Ab + kt * 64, dstA0);
    gload16(Ab + kt * 64 + rstep, dstA0 + 4096);
    gload16(Bb + kt * 64, dstB0);
    gload16(Bb + kt * 64 + rstep, dstB0 + 4096);
    __syncthreads();
    bf16x8 af[4], bfr[4];
#pragma unroll
    for (int m = 0; m < 4; ++m) {
      int row = wr * 64 + m * 16 + cl;
      af[m] = *(const bf16x8*)((const char*)As + row * 64 + ((g ^ (row & 3)) << 4));
    }
#pragma unroll
    for (int n = 0; n < 4; ++n) {
      int row = wc * 64 + n * 16 + cl;
      bfr[n] = *(const bf16x8*)((const char*)Bs + row * 64 + ((g ^ (row & 3)) << 4));
    }
#pragma unroll
    for (int m = 0; m < 4; ++m)
#pragma unroll
      for (int n = 0; n < 4; ++n)
        acc[m][n] = mfma16(af[m], bfr[n], acc[m][n]);
  }

  if (MODE == 0) {
#pragma unroll
    for (int n = 0; n < 4; ++n) {
      int col = (int)n0 + wc * 64 + n * 16 + cl;
      float bv = bprj[col];
#pragma unroll
      for (int m = 0; m < 4; ++m)
#pragma unroll
        for (int r = 0; r < 4; ++r) {
          long row = m0 + wr * 64 + m * 16 + 4 * g + r;
          fout[row * NC + col] = acc[m][n][r] + bv;
        }
    }
    return;
  }

  // ---- fused RMS / RoPE epilogue ----
  const int ct = blockIdx.y;
  const int s_idx = ct / Hh, h = ct % Hh;
  const int bb = (int)(m0 / rowsPerB);
  const int bh = bb * Hh + h;
  const int seq0 = (int)(m0 % rowsPerB) + wr * 64;
  const bool do_norm = (MODE == 1) ? (s_idx < 2) : (s_idx == 0);
  const bool do_rope = (MODE == 1) && (s_idx < 2);

  if (do_norm) {
    float rs[4][4];
#pragma unroll
    for (int m = 0; m < 4; ++m)
#pragma unroll
      for (int r = 0; r < 4; ++r) {
        float t = 0.f;
#pragma unroll
        for (int n = 0; n < 4; ++n) t += acc[m][n][r] * acc[m][n][r];
        t += __shfl_xor(t, 1);
        t += __shfl_xor(t, 2);
        t += __shfl_xor(t, 4);
        t += __shfl_xor(t, 8);
        if (cl == 0) red[wc * 128 + wr * 64 + m * 16 + 4 * g + r] = t;
      }
    __syncthreads();
#pragma unroll
    for (int m = 0; m < 4; ++m)
#pragma unroll
      for (int r = 0; r < 4; ++r) {
        int row = wr * 64 + m * 16 + 4 * g + r;
        rs[m][r] = rsqrtf((red[row] + red[128 + row]) * (1.0f / 128.0f) + EPSV);
      }
    const float* nw = (MODE == 1 && s_idx == 0) ? qnw : knw;
    const float nsc = (MODE == 1 && s_idx == 0) ? SCL : 1.0f;
#pragma unroll
    for (int n = 0; n < 4; ++n) {
      float nwv = nw[wc * 64 + n * 16 + cl] * nsc;
#pragma unroll
      for (int m = 0; m < 4; ++m)
#pragma unroll
        for (int r = 0; r < 4; ++r) acc[m][n][r] *= rs[m][r] * nwv;
    }
  }

  if (do_rope && wc == 0) {
#pragma unroll
    for (int m = 0; m < 4; ++m)
#pragma unroll
      for (int r = 0; r < 4; ++r) {
        int seq = seq0 + m * 16 + 4 * g + r;
#pragma unroll
        for (int n = 0; n < 2; ++n) {
          int d = n * 16 + cl;  // 0..31
          float cs = pos[(seq * 32 + d) * 2 + 0];
          float sn = pos[(seq * 32 + d) * 2 + 1];
          float t1 = acc[m][n][r], t2 = acc[m][n + 2][r];
          acc[m][n][r] = t1 * cs - t2 * sn;
          acc[m][n + 2][r] = t1 * sn + t2 * cs;
        }
      }
  }

  u16* ob;
  long sbase;
  if (MODE == 1) {
    if (s_idx == 0) { ob = qout; sbase = (long)bh * Nn; }
    else if (s_idx == 1) { ob = kout; sbase = (long)bh * Ss; }
    else { ob = vout; sbase = (long)bh * Ss; }
  } else {
    ob = (s_idx == 0) ? kout : vout;
    sbase = (long)bh * Ss + Nn;
  }
#pragma unroll
  for (int m = 0; m < 4; ++m)
#pragma unroll
    for (int r = 0; r < 4; ++r) {
      long rowb = (sbase + seq0 + m * 16 + 4 * g + r) * HD;
#pragma unroll
      for (int n = 0; n < 4; ++n)
        ob[rowb + wc * 64 + n * 16 + cl] = f2bf(acc[m][n][r]);
    }
}

// ---------------- flash attention (pipelined LDS staging, swapped QK) ----------------
// Q (BH,Nn,HD) bf16 (pre-scaled by SCL), K (BH,Ss,HD), Vt (BH,HD,Ss), bias (Bz,Ss) f32
// 128 q/block, 4 waves x 32 q (m=2). KV tile 64, double-buffered, 1 barrier/tile.
__global__ __launch_bounds__(256, 2) void k_flash(
    const u16* __restrict__ Q, const u16* __restrict__ K, const u16* __restrict__ Vt,
    const float* __restrict__ bias, u16* __restrict__ Aout) {
  __shared__ __align__(16) u16 Ks[2][64 * 128];
  __shared__ __align__(16) u16 Vs[2][128 * 64];
  __shared__ __align__(16) u16 Ps[4][16 * 64];
  const int tid = threadIdx.x, lane = tid & 63, wid = tid >> 6;
  const int g = lane >> 4, cl = lane & 15;
  const int bh = blockIdx.y, b = bh / Hh, h = bh % Hh;
  const int n0 = blockIdx.x * 128;
  constexpr int NT = Ss / 64;  // 40

  const u16* Qg = Q + ((long)bh * Nn + n0 + wid * 32) * HD;
  const char* Kg = (const char*)(K + (long)bh * Ss * HD);
  const char* Vg = (const char*)(Vt + (long)bh * HD * Ss);
  const float* bg = bias + b * Ss;

  // Q fragments from global (one-time): lane holds row m*16+cl, k-chunk kk*32+g*8
  bf16x8 qf[2][4];
#pragma unroll
  for (int m = 0; m < 2; ++m)
#pragma unroll
    for (int kk = 0; kk < 4; ++kk)
      qf[m][kk] = *(const bf16x8*)(Qg + (m * 16 + cl) * HD + kk * 32 + g * 8);

  // staging (pre-swizzled global source, linear LDS dest)
  const int krow = tid >> 4;
  const char* Ksrc = Kg + krow * 256 + (((tid & 15) ^ (krow & 7)) << 4);
  const int vrow = tid >> 3;
  const char* Vsrc = Vg + (long)vrow * (Ss * 2) + (((tid & 7) ^ (vrow & 7)) << 4);
  const int dsto = (tid & ~63) << 4;

  auto STAGE = [&](int t, int s) {
    char* kd = (char*)Ks[s] + dsto;
    char* vd = (char*)Vs[s] + dsto;
    long kb = (long)t * 64;
#pragma unroll
    for (int i = 0; i < 4; ++i) gload16(Ksrc + kb * 256 + i * (16 * 256), kd + i * 4096);
#pragma unroll
    for (int i = 0; i < 4; ++i) gload16(Vsrc + kb * 2 + (long)i * 32 * (Ss * 2), vd + i * 4096);
  };

  f32x4 ov[2][8] = {};
  float mi[2] = {-3e38f, -3e38f}, li[2] = {0.f, 0.f};
  u16* pt = (u16*)Ps[wid];
  const int h7 = (cl & 7) << 1;

  STAGE(0, 0);
  __syncthreads();
  int cur = 0;
  for (int t = 0; t < NT; ++t) {
    if (t + 1 < NT) STAGE(t + 1, cur ^ 1);
    const bool biased = (t * 64 >= Nn);
    float badd[4][4];
    if (biased) {
#pragma unroll
      for (int n = 0; n < 4; ++n)
#pragma unroll
        for (int r = 0; r < 4; ++r)
          badd[n][r] = bg[t * 64 + n * 16 + 4 * g + r];
    }
    const char* ks = (const char*)Ks[cur];
    const char* vs = (const char*)Vs[cur];

    // S^T = K Q^T : lane holds kv = n*16+4g+r (regs), q = m*16+cl
    f32x4 sc[2][4] = {};
#pragma unroll
    for (int n = 0; n < 4; ++n) {
      int krw = n * 16 + cl;
#pragma unroll
      for (int kk = 0; kk < 4; ++kk) {
        bf16x8 kf = *(const bf16x8*)(ks + krw * 256 + (((kk * 4 + g) ^ (krw & 7)) << 4));
        sc[0][n] = mfma16(kf, qf[0][kk], sc[0][n]);
        sc[1][n] = mfma16(kf, qf[1][kk], sc[1][n]);
      }
    }

    // online softmax: per lane one q-row (q = m*16+cl), kv across regs + g-groups
    float co_s[2];
#pragma unroll
    for (int m = 0; m < 2; ++m) {
      float mx = -3e38f;
#pragma unroll
      for (int n = 0; n < 4; ++n)
#pragma unroll
        for (int r = 0; r < 4; ++r) {
          float s = sc[m][n][r];
          if (biased) s += badd[n][r];
          sc[m][n][r] = s;
          mx = fmaxf(mx, s);
        }
      mx = fmaxf(mx, __shfl_xor(mx, 16));
      mx = fmaxf(mx, __shfl_xor(mx, 32));
      float mnew = fmaxf(mi[m], mx);
      float co = __expf(mi[m] - mnew);
      mi[m] = mnew;
      float rsum = 0.f;
#pragma unroll
      for (int n = 0; n < 4; ++n)
#pragma unroll
        for (int r = 0; r < 4; ++r) {
          float p = __expf(sc[m][n][r] - mnew);
          sc[m][n][r] = p;
          rsum += p;
        }
      rsum += __shfl_xor(rsum, 16);
      rsum += __shfl_xor(rsum, 32);
      li[m] = li[m] * co + rsum;
      co_s[m] = co;
    }

    // rescale O by per-q corr (broadcast from lane cl=4g+r)
#pragma unroll
    for (int m = 0; m < 2; ++m)
#pragma unroll
      for (int r = 0; r < 4; ++r) {
        float cr = __shfl(co_s[m], 4 * g + r, 64);
#pragma unroll
        for (int nd = 0; nd < 8; ++nd) ov[m][nd][r] *= cr;
      }

    // P[q][kv] via packed b64 writes (XOR-swizzled), read back as b128 A-frags
    bf16x8 pf[2][2];
#pragma unroll
    for (int m = 0; m < 2; ++m) {
#pragma unroll
      for (int n = 0; n < 4; ++n) {
        uint2 w;
        w.x = cvtpk(sc[m][n][0], sc[m][n][1]);
        w.y = cvtpk(sc[m][n][2], sc[m][n][3]);
        *(uint2*)((char*)pt + cl * 128 + (((4 * n + g) ^ h7) << 3)) = w;
      }
#pragma unroll
      for (int ks2 = 0; ks2 < 2; ++ks2)
        pf[m][ks2] = *(const bf16x8*)((const char*)pt + cl * 128 +
                                      (((8 * ks2 + 2 * g) ^ h7) << 3));
    }

    // O += P V
#pragma unroll
    for (int nd = 0; nd < 8; ++nd) {
      int vrw = nd * 16 + cl;
#pragma unroll
      for (int ks2 = 0; ks2 < 2; ++ks2) {
        bf16x8 vf = *(const bf16x8*)(vs + vrw * 128 + (((ks2 * 4 + g) ^ (vrw & 7)) << 4));
        ov[0][nd] = mfma16(pf[0][ks2], vf, ov[0][nd]);
        ov[1][nd] = mfma16(pf[1][ks2], vf, ov[1][nd]);
      }
    }
    __syncthreads();
    cur ^= 1;
  }

#pragma unroll
  for (int m = 0; m < 2; ++m) {
    float inv = 1.0f / li[m];
#pragma unroll
    for (int r = 0; r < 4; ++r) {
      float iv = __shfl(inv, 4 * g + r, 64);
      long row = (long)b * Nn + n0 + wid * 32 + m * 16 + 4 * g + r;
      long base = row * Cc + h * HD;
#pragma unroll
      for (int nd = 0; nd < 8; ++nd)
        Aout[base + nd * 16 + cl] = f2bf(ov[m][nd][r] * iv);
    }
  }
}

// ---------------- launcher ----------------

extern "C" void kernel_launch(void* const* d_in, const int* in_sizes, int n_in,
                              void* d_out, int out_size, void* d_ws, size_t ws_size,
                              hipStream_t stream) {
  const float* x = (const float*)d_in[0];
  const float* y = (const float*)d_in[1];
  const float* pos = (const float*)d_in[2];
  const float* ytw = (const float*)d_in[3];
  const float* Wqkv = (const float*)d_in[4];
  const float* Wkv = (const float*)d_in[5];
  const float* qnw = (const float*)d_in[6];
  const float* knw = (const float*)d_in[7];
  const float* Wproj = (const float*)d_in[8];
  const float* bproj = (const float*)d_in[9];
  float* out = (float*)d_out;
  char* ws = (char*)d_ws;

  size_t o = 0;
  auto take = [&](size_t b) {
    char* p = ws + o;
    o += (b + 255) & ~(size_t)255;
    return p;
  };
  u16* xb = (u16*)take((size_t)Bz * Nn * Cc * 2);
  u16* yb = (u16*)take((size_t)Bz * Mm * Cc * 2);
  u16* wqkvt = (u16*)take((size_t)3 * Cc * Cc * 2);
  u16* wkvt = (u16*)take((size_t)2 * Cc * Cc * 2);
  u16* wprjt = (u16*)take((size_t)Cc * Cc * 2);
  u16* qb = (u16*)take((size_t)Bz * Hh * Nn * HD * 2);
  u16* kb = (u16*)take((size_t)Bz * Hh * Ss * HD * 2);
  u16* vb = (u16*)take((size_t)Bz * Hh * Ss * HD * 2);
  u16* vtb = (u16*)take((size_t)Bz * Hh * Ss * HD * 2);
  u16* ab = (u16*)take((size_t)Bz * Nn * Cc * 2);
  float* bias = (float*)take((size_t)Bz * Ss * 4);

  k_convert<<<dim3(Bz * Nn * Cc / 1024), 256, 0, stream>>>(x, xb, Bz * Nn * Cc);
  k_convert<<<dim3(Bz * Mm * Cc / 1024), 256, 0, stream>>>(y, yb, Bz * Mm * Cc);
  k_transpose_conv<<<dim3(3 * Cc / 32, Cc / 32), 256, 0, stream>>>(Wqkv, wqkvt, Cc, 3 * Cc);
  k_transpose_conv<<<dim3(2 * Cc / 32, Cc / 32), 256, 0, stream>>>(Wkv, wkvt, Cc, 2 * Cc);
  k_transpose_conv<<<dim3(Cc / 32, Cc / 32), 256, 0, stream>>>(Wproj, wprjt, Cc, Cc);
  k_bias<<<dim3((Bz * Ss + 255) / 256), 256, 0, stream>>>(ytw, bias);
  k_gemm<1><<<dim3(Bz * Nn / 128, 3 * Cc / 128), 256, 0, stream>>>(
      xb, wqkvt, Cc, 3 * Cc, Nn, pos, qnw, knw, nullptr, qb, kb, vb, nullptr);
  k_gemm<2><<<dim3(Bz * Mm / 128, 2 * Cc / 128), 256, 0, stream>>>(
      yb, wkvt, Cc, 2 * Cc, Mm, pos, qnw, knw, nullptr, nullptr, kb, vb, nullptr);
  k_transpose_v<<<dim3(Ss / 32, HD / 32, Bz * Hh), 256, 0, stream>>>(vb, vtb);
  k_flash<<<dim3(Nn / 128, Bz * Hh), 256, 0, stream>>>(qb, kb, vtb, bias, ab);
  k_gemm<0><<<dim3(Bz * Nn / 128, Cc / 128), 256, 0, stream>>>(
      ab, wprjt, Cc, Cc, Nn, nullptr, nullptr, nullptr, bproj, nullptr, nullptr, nullptr, out);
}

// Round 4
// 411.377 us; speedup vs baseline: 1.8576x; 1.0389x over previous
//
#include <hip/hip_runtime.h>

typedef unsigned short u16;
typedef short bf16x8 __attribute__((ext_vector_type(8)));
typedef float f32x4 __attribute__((ext_vector_type(4)));
typedef u16 u16x4 __attribute__((ext_vector_type(4)));

#define DEVFN static __device__ __forceinline__

constexpr int Bz = 2, Nn = 2048, Mm = 512, Cc = 1536, Hh = 12, HD = 128;
constexpr int Ss = Nn + Mm;                 // 2560
constexpr float EPSV = 1e-6f;
constexpr float SCL = 0.08838834764831845f; // 128^-0.5

DEVFN u16 f2bf(float f) {
  union { float f; unsigned u; } v; v.f = f;
  unsigned r = v.u + 0x7fffu + ((v.u >> 16) & 1u);
  return (u16)(r >> 16);
}

DEVFN unsigned cvtpk(float lo, float hi) {
  unsigned r;
  asm("v_cvt_pk_bf16_f32 %0, %1, %2" : "=v"(r) : "v"(lo), "v"(hi));
  return r;
}

DEVFN void gload16(const void* g, void* l) {
  __builtin_amdgcn_global_load_lds((const __attribute__((address_space(1))) void*)g,
                                   (__attribute__((address_space(3))) void*)l, 16, 0, 0);
}

DEVFN f32x4 mfma16(bf16x8 a, bf16x8 b, f32x4 c) {
  return __builtin_amdgcn_mfma_f32_16x16x32_bf16(a, b, c, 0, 0, 0);
}

// ---------------- prep kernels ----------------

__global__ void k_convert(const float* __restrict__ in, u16* __restrict__ out, int n) {
  int i = (blockIdx.x * blockDim.x + threadIdx.x) * 4;
  if (i < n) {
    float4 v = *(const float4*)(in + i);
    u16x4 o = { f2bf(v.x), f2bf(v.y), f2bf(v.z), f2bf(v.w) };
    *(u16x4*)(out + i) = o;
  }
}

// in: f32 (R x Ccols) row-major -> out: bf16 (Ccols x R)
__global__ void k_transpose_conv(const float* __restrict__ in, u16* __restrict__ out,
                                 int R, int Ccols) {
  __shared__ float t[32][33];
  int c0 = blockIdx.x * 32, r0 = blockIdx.y * 32;
  int lr = threadIdx.x >> 5, lc = threadIdx.x & 31;
#pragma unroll
  for (int i = 0; i < 4; ++i)
    t[lr + 8 * i][lc] = in[(long)(r0 + lr + 8 * i) * Ccols + c0 + lc];
  __syncthreads();
#pragma unroll
  for (int i = 0; i < 4; ++i)
    out[(long)(c0 + lr + 8 * i) * R + r0 + lc] = f2bf(t[lc][lr + 8 * i]);
}

__global__ void k_bias(const float* __restrict__ w, float* __restrict__ bias) {
  int i = blockIdx.x * 256 + threadIdx.x;
  if (i < Bz * Ss) {
    int b = i / Ss, s = i % Ss;
    bias[i] = (s < Nn) ? 0.0f : logf(fmaxf(w[b * Mm + s - Nn], 1e-4f));
  }
}

// ---------------- GEMM (A row-major MxK bf16, Bt = B^T (N x K) bf16) ----------------
// T3-minimum pipeline: dbuf LDS, BK=64, barrier -> STAGE(next) -> compute(cur).
// MODE 0: plain + bproj -> f32 out
// MODE 1: qkv epilogue  (s=0 q: RMS+RoPE+SCL, s=1 kx: RMS+RoPE, s=2 vx -> transposed)
// MODE 2: kv  epilogue  (s=0 ky: RMS only -> k[N..], s=1 vy -> transposed v[N..])
template <int MODE>
__global__ __launch_bounds__(256, 2) void k_gemm(
    const u16* __restrict__ A, const u16* __restrict__ Bt,
    int K, int NC, int rowsPerB,
    const float* __restrict__ pos, const float* __restrict__ qnw,
    const float* __restrict__ knw, const float* __restrict__ bprj,
    u16* __restrict__ qout, u16* __restrict__ kout, u16* __restrict__ vout,
    float* __restrict__ fout) {
  __shared__ __align__(16) u16 As[2][128 * 64];
  __shared__ __align__(16) u16 Bs[2][128 * 64];
  __shared__ float red[256];
  const int tid = threadIdx.x;
  const int lane = tid & 63;
  const int wid = tid >> 6;
  const int g = lane >> 4, cl = lane & 15;
  const int wr = wid >> 1, wc = wid & 1;
  const long m0 = (long)blockIdx.x * 128, n0 = (long)blockIdx.y * 128;

  f32x4 acc[4][4] = {};

  // staging: dest slot sI = i*256+tid -> row = sI>>3 (=i*32 + tid>>3), blk = tid&7.
  // LDS[row][blk] holds A[row][blk ^ (row&7)] (16B blocks).
  const int arow0 = tid >> 3;
  const int sxb = (((tid & 7) ^ (arow0 & 7)) << 4);
  const long K2 = (long)K * 2;
  const char* Abase = (const char*)A + (m0 + arow0) * K2 + sxb;
  const char* Bbase = (const char*)Bt + (n0 + arow0) * K2 + sxb;
  const int dtid = tid * 16;

  auto STAGE = [&](int kt, int s) {
    char* ad = (char*)As[s];
    char* bd = (char*)Bs[s];
    const long ko = (long)kt * 128;
#pragma unroll
    for (int i = 0; i < 4; ++i) {
      gload16(Abase + i * 32 * K2 + ko, ad + i * 4096 + dtid);
      gload16(Bbase + i * 32 * K2 + ko, bd + i * 4096 + dtid);
    }
  };

  const int nt = K / 64;
  STAGE(0, 0);
  int cur = 0;
  for (int kt = 0; kt < nt; ++kt) {
    __syncthreads();                       // buf[cur] staged; prev reads done
    if (kt + 1 < nt) STAGE(kt + 1, cur ^ 1);  // in flight under compute
    const char* as = (const char*)As[cur];
    const char* bs = (const char*)Bs[cur];
#pragma unroll
    for (int s = 0; s < 2; ++s) {
      bf16x8 af[4], bfr[4];
#pragma unroll
      for (int m = 0; m < 4; ++m) {
        int row = wr * 64 + m * 16 + cl;
        af[m] = *(const bf16x8*)(as + row * 128 + (((s * 4 + g) ^ (row & 7)) << 4));
      }
#pragma unroll
      for (int n = 0; n < 4; ++n) {
        int row = wc * 64 + n * 16 + cl;
        bfr[n] = *(const bf16x8*)(bs + row * 128 + (((s * 4 + g) ^ (row & 7)) << 4));
      }
#pragma unroll
      for (int m = 0; m < 4; ++m)
#pragma unroll
        for (int n = 0; n < 4; ++n)
          acc[m][n] = mfma16(af[m], bfr[n], acc[m][n]);
    }
    cur ^= 1;
  }

  if (MODE == 0) {
#pragma unroll
    for (int n = 0; n < 4; ++n) {
      int col = (int)n0 + wc * 64 + n * 16 + cl;
      float bv = bprj[col];
#pragma unroll
      for (int m = 0; m < 4; ++m)
#pragma unroll
        for (int r = 0; r < 4; ++r) {
          long row = m0 + wr * 64 + m * 16 + 4 * g + r;
          fout[row * NC + col] = acc[m][n][r] + bv;
        }
    }
    return;
  }

  // ---- fused epilogues ----
  const int ct = blockIdx.y;
  const int s_idx = ct / Hh, h = ct % Hh;
  const int bb = (int)(m0 / rowsPerB);
  const int bh = bb * Hh + h;
  const int seq0 = (int)(m0 % rowsPerB) + wr * 64;
  const bool is_v = (MODE == 1) ? (s_idx == 2) : (s_idx == 1);
  const bool do_norm = !is_v;
  const bool do_rope = (MODE == 1) && (s_idx < 2);

  if (is_v) {
    // transposed V write: vt[(bh*HD + d)*Ss + s], 4 consecutive s per store
    const long s0 = (MODE == 2 ? Nn : 0) + seq0;
#pragma unroll
    for (int m = 0; m < 4; ++m) {
      long sb = s0 + m * 16 + 4 * g;
#pragma unroll
      for (int n = 0; n < 4; ++n) {
        int d = wc * 64 + n * 16 + cl;
        u16x4 pk = { f2bf(acc[m][n][0]), f2bf(acc[m][n][1]),
                     f2bf(acc[m][n][2]), f2bf(acc[m][n][3]) };
        *(u16x4*)(vout + ((long)bh * HD + d) * Ss + sb) = pk;
      }
    }
    return;
  }

  if (do_norm) {
    float rs[4][4];
#pragma unroll
    for (int m = 0; m < 4; ++m)
#pragma unroll
      for (int r = 0; r < 4; ++r) {
        float t = 0.f;
#pragma unroll
        for (int n = 0; n < 4; ++n) t += acc[m][n][r] * acc[m][n][r];
        t += __shfl_xor(t, 1);
        t += __shfl_xor(t, 2);
        t += __shfl_xor(t, 4);
        t += __shfl_xor(t, 8);
        if (cl == 0) red[wc * 128 + wr * 64 + m * 16 + 4 * g + r] = t;
      }
    __syncthreads();
#pragma unroll
    for (int m = 0; m < 4; ++m)
#pragma unroll
      for (int r = 0; r < 4; ++r) {
        int row = wr * 64 + m * 16 + 4 * g + r;
        rs[m][r] = rsqrtf((red[row] + red[128 + row]) * (1.0f / 128.0f) + EPSV);
      }
    const float* nw = (MODE == 1 && s_idx == 0) ? qnw : knw;
    const float nsc = (MODE == 1 && s_idx == 0) ? SCL : 1.0f;
#pragma unroll
    for (int n = 0; n < 4; ++n) {
      float nwv = nw[wc * 64 + n * 16 + cl] * nsc;
#pragma unroll
      for (int m = 0; m < 4; ++m)
#pragma unroll
        for (int r = 0; r < 4; ++r) acc[m][n][r] *= rs[m][r] * nwv;
    }
  }

  if (do_rope && wc == 0) {
#pragma unroll
    for (int m = 0; m < 4; ++m)
#pragma unroll
      for (int r = 0; r < 4; ++r) {
        int seq = seq0 + m * 16 + 4 * g + r;
#pragma unroll
        for (int n = 0; n < 2; ++n) {
          int d = n * 16 + cl;  // 0..31
          float cs = pos[(seq * 32 + d) * 2 + 0];
          float sn = pos[(seq * 32 + d) * 2 + 1];
          float t1 = acc[m][n][r], t2 = acc[m][n + 2][r];
          acc[m][n][r] = t1 * cs - t2 * sn;
          acc[m][n + 2][r] = t1 * sn + t2 * cs;
        }
      }
  }

  u16* ob;
  long sbase;
  if (MODE == 1) {
    if (s_idx == 0) { ob = qout; sbase = (long)bh * Nn; }
    else { ob = kout; sbase = (long)bh * Ss; }
  } else {
    ob = kout;
    sbase = (long)bh * Ss + Nn;
  }
#pragma unroll
  for (int m = 0; m < 4; ++m)
#pragma unroll
    for (int r = 0; r < 4; ++r) {
      long rowb = (sbase + seq0 + m * 16 + 4 * g + r) * HD;
#pragma unroll
      for (int n = 0; n < 4; ++n)
        ob[rowb + wc * 64 + n * 16 + cl] = f2bf(acc[m][n][r]);
    }
}

// ---------------- flash attention (pipelined LDS staging, swapped QK) ----------------
// Q (BH,Nn,HD) bf16 (pre-scaled by SCL), K (BH,Ss,HD), Vt (BH,HD,Ss), bias (Bz,Ss) f32
// 128 q/block, 4 waves x 32 q (m=2). KV tile 64, double-buffered, 1 barrier/tile.
__global__ __launch_bounds__(256, 2) void k_flash(
    const u16* __restrict__ Q, const u16* __restrict__ K, const u16* __restrict__ Vt,
    const float* __restrict__ bias, u16* __restrict__ Aout) {
  __shared__ __align__(16) u16 Ks[2][64 * 128];
  __shared__ __align__(16) u16 Vs[2][128 * 64];
  __shared__ __align__(16) u16 Ps[4][16 * 64];
  const int tid = threadIdx.x, lane = tid & 63, wid = tid >> 6;
  const int g = lane >> 4, cl = lane & 15;
  const int bh = blockIdx.y, b = bh / Hh, h = bh % Hh;
  const int n0 = blockIdx.x * 128;
  constexpr int NT = Ss / 64;  // 40

  const u16* Qg = Q + ((long)bh * Nn + n0 + wid * 32) * HD;
  const char* Kg = (const char*)(K + (long)bh * Ss * HD);
  const char* Vg = (const char*)(Vt + (long)bh * HD * Ss);
  const float* bg = bias + b * Ss;

  // Q fragments from global (one-time): lane holds row m*16+cl, k-chunk kk*32+g*8
  bf16x8 qf[2][4];
#pragma unroll
  for (int m = 0; m < 2; ++m)
#pragma unroll
    for (int kk = 0; kk < 4; ++kk)
      qf[m][kk] = *(const bf16x8*)(Qg + (m * 16 + cl) * HD + kk * 32 + g * 8);

  // staging (pre-swizzled global source, linear LDS dest)
  const int krow = tid >> 4;
  const char* Ksrc = Kg + krow * 256 + (((tid & 15) ^ (krow & 7)) << 4);
  const int vrow = tid >> 3;
  const char* Vsrc = Vg + (long)vrow * (Ss * 2) + (((tid & 7) ^ (vrow & 7)) << 4);
  const int dsto = (tid & ~63) << 4;

  auto STAGE = [&](int t, int s) {
    char* kd = (char*)Ks[s] + dsto;
    char* vd = (char*)Vs[s] + dsto;
    long kb = (long)t * 64;
#pragma unroll
    for (int i = 0; i < 4; ++i) gload16(Ksrc + kb * 256 + i * (16 * 256), kd + i * 4096);
#pragma unroll
    for (int i = 0; i < 4; ++i) gload16(Vsrc + kb * 2 + (long)i * 32 * (Ss * 2), vd + i * 4096);
  };

  f32x4 ov[2][8] = {};
  float mi[2] = {-3e38f, -3e38f}, li[2] = {0.f, 0.f};
  u16* pt = (u16*)Ps[wid];
  const int h7 = (cl & 7) << 1;

  STAGE(0, 0);
  __syncthreads();
  int cur = 0;
  for (int t = 0; t < NT; ++t) {
    if (t + 1 < NT) STAGE(t + 1, cur ^ 1);
    const bool biased = (t * 64 >= Nn);
    float badd[4][4];
    if (biased) {
#pragma unroll
      for (int n = 0; n < 4; ++n)
#pragma unroll
        for (int r = 0; r < 4; ++r)
          badd[n][r] = bg[t * 64 + n * 16 + 4 * g + r];
    }
    const char* ks = (const char*)Ks[cur];
    const char* vs = (const char*)Vs[cur];

    // S^T = K Q^T : lane holds kv = n*16+4g+r (regs), q = m*16+cl
    f32x4 sc[2][4] = {};
#pragma unroll
    for (int n = 0; n < 4; ++n) {
      int krw = n * 16 + cl;
#pragma unroll
      for (int kk = 0; kk < 4; ++kk) {
        bf16x8 kf = *(const bf16x8*)(ks + krw * 256 + (((kk * 4 + g) ^ (krw & 7)) << 4));
        sc[0][n] = mfma16(kf, qf[0][kk], sc[0][n]);
        sc[1][n] = mfma16(kf, qf[1][kk], sc[1][n]);
      }
    }

    // online softmax: per lane one q-row (q = m*16+cl), kv across regs + g-groups
    float co_s[2];
#pragma unroll
    for (int m = 0; m < 2; ++m) {
      float mx = -3e38f;
#pragma unroll
      for (int n = 0; n < 4; ++n)
#pragma unroll
        for (int r = 0; r < 4; ++r) {
          float s = sc[m][n][r];
          if (biased) s += badd[n][r];
          sc[m][n][r] = s;
          mx = fmaxf(mx, s);
        }
      mx = fmaxf(mx, __shfl_xor(mx, 16));
      mx = fmaxf(mx, __shfl_xor(mx, 32));
      float mnew = fmaxf(mi[m], mx);
      float co = __expf(mi[m] - mnew);
      mi[m] = mnew;
      float rsum = 0.f;
#pragma unroll
      for (int n = 0; n < 4; ++n)
#pragma unroll
        for (int r = 0; r < 4; ++r) {
          float p = __expf(sc[m][n][r] - mnew);
          sc[m][n][r] = p;
          rsum += p;
        }
      rsum += __shfl_xor(rsum, 16);
      rsum += __shfl_xor(rsum, 32);
      li[m] = li[m] * co + rsum;
      co_s[m] = co;
    }

    // rescale O by per-q corr (broadcast from lane cl=4g+r)
#pragma unroll
    for (int m = 0; m < 2; ++m)
#pragma unroll
      for (int r = 0; r < 4; ++r) {
        float cr = __shfl(co_s[m], 4 * g + r, 64);
#pragma unroll
        for (int nd = 0; nd < 8; ++nd) ov[m][nd][r] *= cr;
      }

    // P[q][kv] via packed b64 writes (XOR-swizzled), read back as b128 A-frags
    bf16x8 pf[2][2];
#pragma unroll
    for (int m = 0; m < 2; ++m) {
#pragma unroll
      for (int n = 0; n < 4; ++n) {
        uint2 w;
        w.x = cvtpk(sc[m][n][0], sc[m][n][1]);
        w.y = cvtpk(sc[m][n][2], sc[m][n][3]);
        *(uint2*)((char*)pt + cl * 128 + (((4 * n + g) ^ h7) << 3)) = w;
      }
#pragma unroll
      for (int ks2 = 0; ks2 < 2; ++ks2)
        pf[m][ks2] = *(const bf16x8*)((const char*)pt + cl * 128 +
                                      (((8 * ks2 + 2 * g) ^ h7) << 3));
    }

    // O += P V
#pragma unroll
    for (int nd = 0; nd < 8; ++nd) {
      int vrw = nd * 16 + cl;
#pragma unroll
      for (int ks2 = 0; ks2 < 2; ++ks2) {
        bf16x8 vf = *(const bf16x8*)(vs + vrw * 128 + (((ks2 * 4 + g) ^ (vrw & 7)) << 4));
        ov[0][nd] = mfma16(pf[0][ks2], vf, ov[0][nd]);
        ov[1][nd] = mfma16(pf[1][ks2], vf, ov[1][nd]);
      }
    }
    __syncthreads();
    cur ^= 1;
  }

#pragma unroll
  for (int m = 0; m < 2; ++m) {
    float inv = 1.0f / li[m];
#pragma unroll
    for (int r = 0; r < 4; ++r) {
      float iv = __shfl(inv, 4 * g + r, 64);
      long row = (long)b * Nn + n0 + wid * 32 + m * 16 + 4 * g + r;
      long base = row * Cc + h * HD;
#pragma unroll
      for (int nd = 0; nd < 8; ++nd)
        Aout[base + nd * 16 + cl] = f2bf(ov[m][nd][r] * iv);
    }
  }
}

// ---------------- launcher ----------------

extern "C" void kernel_launch(void* const* d_in, const int* in_sizes, int n_in,
                              void* d_out, int out_size, void* d_ws, size_t ws_size,
                              hipStream_t stream) {
  const float* x = (const float*)d_in[0];
  const float* y = (const float*)d_in[1];
  const float* pos = (const float*)d_in[2];
  const float* ytw = (const float*)d_in[3];
  const float* Wqkv = (const float*)d_in[4];
  const float* Wkv = (const float*)d_in[5];
  const float* qnw = (const float*)d_in[6];
  const float* knw = (const float*)d_in[7];
  const float* Wproj = (const float*)d_in[8];
  const float* bproj = (const float*)d_in[9];
  float* out = (float*)d_out;
  char* ws = (char*)d_ws;

  size_t o = 0;
  auto take = [&](size_t b) {
    char* p = ws + o;
    o += (b + 255) & ~(size_t)255;
    return p;
  };
  u16* xb = (u16*)take((size_t)Bz * Nn * Cc * 2);
  u16* yb = (u16*)take((size_t)Bz * Mm * Cc * 2);
  u16* wqkvt = (u16*)take((size_t)3 * Cc * Cc * 2);
  u16* wkvt = (u16*)take((size_t)2 * Cc * Cc * 2);
  u16* wprjt = (u16*)take((size_t)Cc * Cc * 2);
  u16* qb = (u16*)take((size_t)Bz * Hh * Nn * HD * 2);
  u16* kb = (u16*)take((size_t)Bz * Hh * Ss * HD * 2);
  u16* vtb = (u16*)take((size_t)Bz * Hh * Ss * HD * 2);
  u16* ab = (u16*)take((size_t)Bz * Nn * Cc * 2);
  float* bias = (float*)take((size_t)Bz * Ss * 4);

  k_convert<<<dim3(Bz * Nn * Cc / 1024), 256, 0, stream>>>(x, xb, Bz * Nn * Cc);
  k_convert<<<dim3(Bz * Mm * Cc / 1024), 256, 0, stream>>>(y, yb, Bz * Mm * Cc);
  k_transpose_conv<<<dim3(3 * Cc / 32, Cc / 32), 256, 0, stream>>>(Wqkv, wqkvt, Cc, 3 * Cc);
  k_transpose_conv<<<dim3(2 * Cc / 32, Cc / 32), 256, 0, stream>>>(Wkv, wkvt, Cc, 2 * Cc);
  k_transpose_conv<<<dim3(Cc / 32, Cc / 32), 256, 0, stream>>>(Wproj, wprjt, Cc, Cc);
  k_bias<<<dim3((Bz * Ss + 255) / 256), 256, 0, stream>>>(ytw, bias);
  k_gemm<1><<<dim3(Bz * Nn / 128, 3 * Cc / 128), 256, 0, stream>>>(
      xb, wqkvt, Cc, 3 * Cc, Nn, pos, qnw, knw, nullptr, qb, kb, vtb, nullptr);
  k_gemm<2><<<dim3(Bz * Mm / 128, 2 * Cc / 128), 256, 0, stream>>>(
      yb, wkvt, Cc, 2 * Cc, Mm, pos, qnw, knw, nullptr, nullptr, kb, vtb, nullptr);
  k_flash<<<dim3(Nn / 128, Bz * Hh), 256, 0, stream>>>(qb, kb, vtb, bias, ab);
  k_gemm<0><<<dim3(Bz * Nn / 128, Cc / 128), 256, 0, stream>>>(
      ab, wprjt, Cc, Cc, Nn, nullptr, nullptr, nullptr, bproj, nullptr, nullptr, nullptr, out);
}

// Round 5
// 401.467 us; speedup vs baseline: 1.9034x; 1.0247x over previous
//
#include <hip/hip_runtime.h>

typedef unsigned short u16;
typedef short bf16x8 __attribute__((ext_vector_type(8)));
typedef float f32x4 __attribute__((ext_vector_type(4)));
typedef u16 u16x4 __attribute__((ext_vector_type(4)));

#define DEVFN static __device__ __forceinline__

constexpr int Bz = 2, Nn = 2048, Mm = 512, Cc = 1536, Hh = 12, HD = 128;
constexpr int Ss = Nn + Mm;                 // 2560
constexpr float EPSV = 1e-6f;
constexpr float SCL = 0.08838834764831845f; // 128^-0.5

DEVFN u16 f2bf(float f) {
  union { float f; unsigned u; } v; v.f = f;
  unsigned r = v.u + 0x7fffu + ((v.u >> 16) & 1u);
  return (u16)(r >> 16);
}

DEVFN unsigned cvtpk(float lo, float hi) {
  unsigned r;
  asm("v_cvt_pk_bf16_f32 %0, %1, %2" : "=v"(r) : "v"(lo), "v"(hi));
  return r;
}

DEVFN void gload16(const void* g, void* l) {
  __builtin_amdgcn_global_load_lds((const __attribute__((address_space(1))) void*)g,
                                   (__attribute__((address_space(3))) void*)l, 16, 0, 0);
}

DEVFN f32x4 mfma16(bf16x8 a, bf16x8 b, f32x4 c) {
  return __builtin_amdgcn_mfma_f32_16x16x32_bf16(a, b, c, 0, 0, 0);
}

// XCD-chunked block swizzle (requires nwg % 8 == 0; all our grids satisfy this)
DEVFN int xcdswz(int hw, int nwg) {
  int q = nwg >> 3;
  return (hw & 7) * q + (hw >> 3);
}

// ---------------- prep kernels ----------------

__global__ void k_convert(const float* __restrict__ in, u16* __restrict__ out, int n) {
  int i = (blockIdx.x * blockDim.x + threadIdx.x) * 4;
  if (i < n) {
    float4 v = *(const float4*)(in + i);
    u16x4 o = { f2bf(v.x), f2bf(v.y), f2bf(v.z), f2bf(v.w) };
    *(u16x4*)(out + i) = o;
  }
}

// in: f32 (R x Ccols) row-major -> out: bf16 (Ccols x R)
__global__ void k_transpose_conv(const float* __restrict__ in, u16* __restrict__ out,
                                 int R, int Ccols) {
  __shared__ float t[32][33];
  int c0 = blockIdx.x * 32, r0 = blockIdx.y * 32;
  int lr = threadIdx.x >> 5, lc = threadIdx.x & 31;
#pragma unroll
  for (int i = 0; i < 4; ++i)
    t[lr + 8 * i][lc] = in[(long)(r0 + lr + 8 * i) * Ccols + c0 + lc];
  __syncthreads();
#pragma unroll
  for (int i = 0; i < 4; ++i)
    out[(long)(c0 + lr + 8 * i) * R + r0 + lc] = f2bf(t[lc][lr + 8 * i]);
}

__global__ void k_bias(const float* __restrict__ w, float* __restrict__ bias) {
  int i = blockIdx.x * 256 + threadIdx.x;
  if (i < Bz * Ss) {
    int b = i / Ss, s = i % Ss;
    bias[i] = (s < Nn) ? 0.0f : logf(fmaxf(w[b * Mm + s - Nn], 1e-4f));
  }
}

// ---------------- GEMM (A row-major MxK bf16, Bt = B^T (N x K) bf16) ----------------
// Single-buffer BK=64, 33KB LDS -> 4 blocks/CU; cross-block phase diversity hides staging.
// MODE 0: plain + bproj -> f32 out
// MODE 1: qkv epilogue  (s=0 q: RMS+RoPE+SCL, s=1 kx: RMS+RoPE, s=2 vx -> transposed)
// MODE 2: kv  epilogue  (s=0 ky: RMS only -> k[N..], s=1 vy -> transposed v[N..])
template <int MODE>
__global__ __launch_bounds__(256, MODE == 0 ? 4 : 3) void k_gemm(
    const u16* __restrict__ A, const u16* __restrict__ Bt,
    int K, int NC, int rowsPerB,
    const float* __restrict__ pos, const float* __restrict__ qnw,
    const float* __restrict__ knw, const float* __restrict__ bprj,
    u16* __restrict__ qout, u16* __restrict__ kout, u16* __restrict__ vout,
    float* __restrict__ fout) {
  __shared__ __align__(16) u16 As[128 * 64];
  __shared__ __align__(16) u16 Bs[128 * 64];
  __shared__ float red[256];
  const int tid = threadIdx.x;
  const int lane = tid & 63;
  const int wid = tid >> 6;
  const int g = lane >> 4, cl = lane & 15;
  const int wr = wid >> 1, wc = wid & 1;

  // XCD-chunked swizzle of the block id
  const int gx = gridDim.x;
  const int hw = blockIdx.x + gx * blockIdx.y;
  const int wg = xcdswz(hw, gx * gridDim.y);
  const int bx = wg % gx, by = wg / gx;
  const long m0 = (long)bx * 128, n0 = (long)by * 128;

  f32x4 acc[4][4] = {};

  const int arow0 = tid >> 3;
  const int sxb = (((tid & 7) ^ (arow0 & 7)) << 4);
  const long K2 = (long)K * 2;
  const char* Abase = (const char*)A + (m0 + arow0) * K2 + sxb;
  const char* Bbase = (const char*)Bt + (n0 + arow0) * K2 + sxb;
  const int dtid = tid * 16;

  const int nt = K / 64;
  for (int kt = 0; kt < nt; ++kt) {
    __syncthreads();  // previous iteration's reads complete
    const long ko = (long)kt * 128;
#pragma unroll
    for (int i = 0; i < 4; ++i) {
      gload16(Abase + i * 32 * K2 + ko, (char*)As + i * 4096 + dtid);
      gload16(Bbase + i * 32 * K2 + ko, (char*)Bs + i * 4096 + dtid);
    }
    __syncthreads();  // staged data visible
    __builtin_amdgcn_s_setprio(1);
#pragma unroll
    for (int s = 0; s < 2; ++s) {
      bf16x8 af[4], bfr[4];
#pragma unroll
      for (int m = 0; m < 4; ++m) {
        int row = wr * 64 + m * 16 + cl;
        af[m] = *(const bf16x8*)((const char*)As + row * 128 + (((s * 4 + g) ^ (row & 7)) << 4));
      }
#pragma unroll
      for (int n = 0; n < 4; ++n) {
        int row = wc * 64 + n * 16 + cl;
        bfr[n] = *(const bf16x8*)((const char*)Bs + row * 128 + (((s * 4 + g) ^ (row & 7)) << 4));
      }
#pragma unroll
      for (int m = 0; m < 4; ++m)
#pragma unroll
        for (int n = 0; n < 4; ++n)
          acc[m][n] = mfma16(af[m], bfr[n], acc[m][n]);
    }
    __builtin_amdgcn_s_setprio(0);
  }

  if (MODE == 0) {
#pragma unroll
    for (int n = 0; n < 4; ++n) {
      int col = (int)n0 + wc * 64 + n * 16 + cl;
      float bv = bprj[col];
#pragma unroll
      for (int m = 0; m < 4; ++m)
#pragma unroll
        for (int r = 0; r < 4; ++r) {
          long row = m0 + wr * 64 + m * 16 + 4 * g + r;
          fout[row * NC + col] = acc[m][n][r] + bv;
        }
    }
    return;
  }

  // ---- fused epilogues ----
  const int ct = by;
  const int s_idx = ct / Hh, h = ct % Hh;
  const int bb = (int)(m0 / rowsPerB);
  const int bh = bb * Hh + h;
  const int seq0 = (int)(m0 % rowsPerB) + wr * 64;
  const bool is_v = (MODE == 1) ? (s_idx == 2) : (s_idx == 1);
  const bool do_norm = !is_v;
  const bool do_rope = (MODE == 1) && (s_idx < 2);

  if (is_v) {
    const long s0 = (MODE == 2 ? Nn : 0) + seq0;
#pragma unroll
    for (int m = 0; m < 4; ++m) {
      long sb = s0 + m * 16 + 4 * g;
#pragma unroll
      for (int n = 0; n < 4; ++n) {
        int d = wc * 64 + n * 16 + cl;
        u16x4 pk = { f2bf(acc[m][n][0]), f2bf(acc[m][n][1]),
                     f2bf(acc[m][n][2]), f2bf(acc[m][n][3]) };
        *(u16x4*)(vout + ((long)bh * HD + d) * Ss + sb) = pk;
      }
    }
    return;
  }

  if (do_norm) {
    float rs[4][4];
#pragma unroll
    for (int m = 0; m < 4; ++m)
#pragma unroll
      for (int r = 0; r < 4; ++r) {
        float t = 0.f;
#pragma unroll
        for (int n = 0; n < 4; ++n) t += acc[m][n][r] * acc[m][n][r];
        t += __shfl_xor(t, 1);
        t += __shfl_xor(t, 2);
        t += __shfl_xor(t, 4);
        t += __shfl_xor(t, 8);
        if (cl == 0) red[wc * 128 + wr * 64 + m * 16 + 4 * g + r] = t;
      }
    __syncthreads();
#pragma unroll
    for (int m = 0; m < 4; ++m)
#pragma unroll
      for (int r = 0; r < 4; ++r) {
        int row = wr * 64 + m * 16 + 4 * g + r;
        rs[m][r] = rsqrtf((red[row] + red[128 + row]) * (1.0f / 128.0f) + EPSV);
      }
    const float* nw = (MODE == 1 && s_idx == 0) ? qnw : knw;
    const float nsc = (MODE == 1 && s_idx == 0) ? SCL : 1.0f;
#pragma unroll
    for (int n = 0; n < 4; ++n) {
      float nwv = nw[wc * 64 + n * 16 + cl] * nsc;
#pragma unroll
      for (int m = 0; m < 4; ++m)
#pragma unroll
        for (int r = 0; r < 4; ++r) acc[m][n][r] *= rs[m][r] * nwv;
    }
  }

  if (do_rope && wc == 0) {
#pragma unroll
    for (int m = 0; m < 4; ++m)
#pragma unroll
      for (int r = 0; r < 4; ++r) {
        int seq = seq0 + m * 16 + 4 * g + r;
#pragma unroll
        for (int n = 0; n < 2; ++n) {
          int d = n * 16 + cl;  // 0..31
          float cs = pos[(seq * 32 + d) * 2 + 0];
          float sn = pos[(seq * 32 + d) * 2 + 1];
          float t1 = acc[m][n][r], t2 = acc[m][n + 2][r];
          acc[m][n][r] = t1 * cs - t2 * sn;
          acc[m][n + 2][r] = t1 * sn + t2 * cs;
        }
      }
  }

  u16* ob;
  long sbase;
  if (MODE == 1) {
    if (s_idx == 0) { ob = qout; sbase = (long)bh * Nn; }
    else { ob = kout; sbase = (long)bh * Ss; }
  } else {
    ob = kout;
    sbase = (long)bh * Ss + Nn;
  }
#pragma unroll
  for (int m = 0; m < 4; ++m)
#pragma unroll
    for (int r = 0; r < 4; ++r) {
      long rowb = (sbase + seq0 + m * 16 + 4 * g + r) * HD;
#pragma unroll
      for (int n = 0; n < 4; ++n)
        ob[rowb + wc * 64 + n * 16 + cl] = f2bf(acc[m][n][r]);
    }
}

// ---------------- flash attention (pipelined LDS staging, swapped QK) ----------------
// Q (BH,Nn,HD) bf16 (pre-scaled by SCL), K (BH,Ss,HD), Vt (BH,HD,Ss), bias (Bz,Ss) f32
// 128 q/block, 4 waves x 32 q (m=2). KV tile 64, double-buffered, 1 barrier/tile.
// XCD swizzle: all 16 q-tiles of a head on one XCD (KV L2-resident).
__global__ __launch_bounds__(256, 2) void k_flash(
    const u16* __restrict__ Q, const u16* __restrict__ K, const u16* __restrict__ Vt,
    const float* __restrict__ bias, u16* __restrict__ Aout) {
  __shared__ __align__(16) u16 Ks[2][64 * 128];
  __shared__ __align__(16) u16 Vs[2][128 * 64];
  __shared__ __align__(16) u16 Ps[4][16 * 64];
  const int tid = threadIdx.x, lane = tid & 63, wid = tid >> 6;
  const int g = lane >> 4, cl = lane & 15;
  const int hw = blockIdx.x + gridDim.x * blockIdx.y;
  const int wg = xcdswz(hw, gridDim.x * gridDim.y);
  const int qt = wg % gridDim.x, bh = wg / gridDim.x;
  const int b = bh / Hh, h = bh % Hh;
  const int n0 = qt * 128;
  constexpr int NT = Ss / 64;  // 40

  const u16* Qg = Q + ((long)bh * Nn + n0 + wid * 32) * HD;
  const char* Kg = (const char*)(K + (long)bh * Ss * HD);
  const char* Vg = (const char*)(Vt + (long)bh * HD * Ss);
  const float* bg = bias + b * Ss;

  bf16x8 qf[2][4];
#pragma unroll
  for (int m = 0; m < 2; ++m)
#pragma unroll
    for (int kk = 0; kk < 4; ++kk)
      qf[m][kk] = *(const bf16x8*)(Qg + (m * 16 + cl) * HD + kk * 32 + g * 8);

  const int krow = tid >> 4;
  const char* Ksrc = Kg + krow * 256 + (((tid & 15) ^ (krow & 7)) << 4);
  const int vrow = tid >> 3;
  const char* Vsrc = Vg + (long)vrow * (Ss * 2) + (((tid & 7) ^ (vrow & 7)) << 4);
  const int dsto = (tid & ~63) << 4;

  auto STAGE = [&](int t, int s) {
    char* kd = (char*)Ks[s] + dsto;
    char* vd = (char*)Vs[s] + dsto;
    long kb = (long)t * 64;
#pragma unroll
    for (int i = 0; i < 4; ++i) gload16(Ksrc + kb * 256 + i * (16 * 256), kd + i * 4096);
#pragma unroll
    for (int i = 0; i < 4; ++i) gload16(Vsrc + kb * 2 + (long)i * 32 * (Ss * 2), vd + i * 4096);
  };

  f32x4 ov[2][8] = {};
  float mi[2] = {-3e38f, -3e38f}, li[2] = {0.f, 0.f};
  u16* pt = (u16*)Ps[wid];
  const int h7 = (cl & 7) << 1;

  STAGE(0, 0);
  __syncthreads();
  int cur = 0;
  for (int t = 0; t < NT; ++t) {
    if (t + 1 < NT) STAGE(t + 1, cur ^ 1);
    const bool biased = (t * 64 >= Nn);
    float badd[4][4];
    if (biased) {
#pragma unroll
      for (int n = 0; n < 4; ++n)
#pragma unroll
        for (int r = 0; r < 4; ++r)
          badd[n][r] = bg[t * 64 + n * 16 + 4 * g + r];
    }
    const char* ks = (const char*)Ks[cur];
    const char* vs = (const char*)Vs[cur];

    // S^T = K Q^T : lane holds kv = n*16+4g+r (regs), q = m*16+cl
    f32x4 sc[2][4] = {};
    __builtin_amdgcn_s_setprio(1);
#pragma unroll
    for (int n = 0; n < 4; ++n) {
      int krw = n * 16 + cl;
#pragma unroll
      for (int kk = 0; kk < 4; ++kk) {
        bf16x8 kf = *(const bf16x8*)(ks + krw * 256 + (((kk * 4 + g) ^ (krw & 7)) << 4));
        sc[0][n] = mfma16(kf, qf[0][kk], sc[0][n]);
        sc[1][n] = mfma16(kf, qf[1][kk], sc[1][n]);
      }
    }
    __builtin_amdgcn_s_setprio(0);

    // online softmax with deferred rescale (T13, THR=8)
    float pmax[2];
#pragma unroll
    for (int m = 0; m < 2; ++m) {
      float mx = -3e38f;
#pragma unroll
      for (int n = 0; n < 4; ++n)
#pragma unroll
        for (int r = 0; r < 4; ++r) {
          float s = sc[m][n][r];
          if (biased) s += badd[n][r];
          sc[m][n][r] = s;
          mx = fmaxf(mx, s);
        }
      mx = fmaxf(mx, __shfl_xor(mx, 16));
      mx = fmaxf(mx, __shfl_xor(mx, 32));
      pmax[m] = mx;
    }
    if (__any((pmax[0] > mi[0] + 8.f) || (pmax[1] > mi[1] + 8.f))) {
      float co_s[2];
#pragma unroll
      for (int m = 0; m < 2; ++m) {
        float mnew = fmaxf(mi[m], pmax[m]);
        co_s[m] = __expf(mi[m] - mnew);
        mi[m] = mnew;
        li[m] *= co_s[m];
      }
#pragma unroll
      for (int m = 0; m < 2; ++m)
#pragma unroll
        for (int r = 0; r < 4; ++r) {
          float cr = __shfl(co_s[m], 4 * g + r, 64);
#pragma unroll
          for (int nd = 0; nd < 8; ++nd) ov[m][nd][r] *= cr;
        }
    }
#pragma unroll
    for (int m = 0; m < 2; ++m) {
      float rsum = 0.f;
#pragma unroll
      for (int n = 0; n < 4; ++n)
#pragma unroll
        for (int r = 0; r < 4; ++r) {
          float p = __expf(sc[m][n][r] - mi[m]);
          sc[m][n][r] = p;
          rsum += p;
        }
      rsum += __shfl_xor(rsum, 16);
      rsum += __shfl_xor(rsum, 32);
      li[m] += rsum;
    }

    // P[q][kv] via packed b64 writes (XOR-swizzled), read back as b128 A-frags
    bf16x8 pf[2][2];
#pragma unroll
    for (int m = 0; m < 2; ++m) {
#pragma unroll
      for (int n = 0; n < 4; ++n) {
        uint2 w;
        w.x = cvtpk(sc[m][n][0], sc[m][n][1]);
        w.y = cvtpk(sc[m][n][2], sc[m][n][3]);
        *(uint2*)((char*)pt + cl * 128 + (((4 * n + g) ^ h7) << 3)) = w;
      }
#pragma unroll
      for (int ks2 = 0; ks2 < 2; ++ks2)
        pf[m][ks2] = *(const bf16x8*)((const char*)pt + cl * 128 +
                                      (((8 * ks2 + 2 * g) ^ h7) << 3));
    }

    // O += P V
    __builtin_amdgcn_s_setprio(1);
#pragma unroll
    for (int nd = 0; nd < 8; ++nd) {
      int vrw = nd * 16 + cl;
#pragma unroll
      for (int ks2 = 0; ks2 < 2; ++ks2) {
        bf16x8 vf = *(const bf16x8*)(vs + vrw * 128 + (((ks2 * 4 + g) ^ (vrw & 7)) << 4));
        ov[0][nd] = mfma16(pf[0][ks2], vf, ov[0][nd]);
        ov[1][nd] = mfma16(pf[1][ks2], vf, ov[1][nd]);
      }
    }
    __builtin_amdgcn_s_setprio(0);
    __syncthreads();
    cur ^= 1;
  }

#pragma unroll
  for (int m = 0; m < 2; ++m) {
    float inv = 1.0f / li[m];
#pragma unroll
    for (int r = 0; r < 4; ++r) {
      float iv = __shfl(inv, 4 * g + r, 64);
      long row = (long)b * Nn + n0 + wid * 32 + m * 16 + 4 * g + r;
      long base = row * Cc + h * HD;
#pragma unroll
      for (int nd = 0; nd < 8; ++nd)
        Aout[base + nd * 16 + cl] = f2bf(ov[m][nd][r] * iv);
    }
  }
}

// ---------------- launcher ----------------

extern "C" void kernel_launch(void* const* d_in, const int* in_sizes, int n_in,
                              void* d_out, int out_size, void* d_ws, size_t ws_size,
                              hipStream_t stream) {
  const float* x = (const float*)d_in[0];
  const float* y = (const float*)d_in[1];
  const float* pos = (const float*)d_in[2];
  const float* ytw = (const float*)d_in[3];
  const float* Wqkv = (const float*)d_in[4];
  const float* Wkv = (const float*)d_in[5];
  const float* qnw = (const float*)d_in[6];
  const float* knw = (const float*)d_in[7];
  const float* Wproj = (const float*)d_in[8];
  const float* bproj = (const float*)d_in[9];
  float* out = (float*)d_out;
  char* ws = (char*)d_ws;

  size_t o = 0;
  auto take = [&](size_t b) {
    char* p = ws + o;
    o += (b + 255) & ~(size_t)255;
    return p;
  };
  u16* xb = (u16*)take((size_t)Bz * Nn * Cc * 2);
  u16* yb = (u16*)take((size_t)Bz * Mm * Cc * 2);
  u16* wqkvt = (u16*)take((size_t)3 * Cc * Cc * 2);
  u16* wkvt = (u16*)take((size_t)2 * Cc * Cc * 2);
  u16* wprjt = (u16*)take((size_t)Cc * Cc * 2);
  u16* qb = (u16*)take((size_t)Bz * Hh * Nn * HD * 2);
  u16* kb = (u16*)take((size_t)Bz * Hh * Ss * HD * 2);
  u16* vtb = (u16*)take((size_t)Bz * Hh * Ss * HD * 2);
  u16* ab = (u16*)take((size_t)Bz * Nn * Cc * 2);
  float* bias = (float*)take((size_t)Bz * Ss * 4);

  k_convert<<<dim3(Bz * Nn * Cc / 1024), 256, 0, stream>>>(x, xb, Bz * Nn * Cc);
  k_convert<<<dim3(Bz * Mm * Cc / 1024), 256, 0, stream>>>(y, yb, Bz * Mm * Cc);
  k_transpose_conv<<<dim3(3 * Cc / 32, Cc / 32), 256, 0, stream>>>(Wqkv, wqkvt, Cc, 3 * Cc);
  k_transpose_conv<<<dim3(2 * Cc / 32, Cc / 32), 256, 0, stream>>>(Wkv, wkvt, Cc, 2 * Cc);
  k_transpose_conv<<<dim3(Cc / 32, Cc / 32), 256, 0, stream>>>(Wproj, wprjt, Cc, Cc);
  k_bias<<<dim3((Bz * Ss + 255) / 256), 256, 0, stream>>>(ytw, bias);
  k_gemm<1><<<dim3(Bz * Nn / 128, 3 * Cc / 128), 256, 0, stream>>>(
      xb, wqkvt, Cc, 3 * Cc, Nn, pos, qnw, knw, nullptr, qb, kb, vtb, nullptr);
  k_gemm<2><<<dim3(Bz * Mm / 128, 2 * Cc / 128), 256, 0, stream>>>(
      yb, wkvt, Cc, 2 * Cc, Mm, pos, qnw, knw, nullptr, nullptr, kb, vtb, nullptr);
  k_flash<<<dim3(Nn / 128, Bz * Hh), 256, 0, stream>>>(qb, kb, vtb, bias, ab);
  k_gemm<0><<<dim3(Bz * Nn / 128, Cc / 128), 256, 0, stream>>>(
      ab, wprjt, Cc, Cc, Nn, nullptr, nullptr, nullptr, bproj, nullptr, nullptr, nullptr, out);
}

// Round 6
// 392.706 us; speedup vs baseline: 1.9459x; 1.0223x over previous
//
#include <hip/hip_runtime.h>

typedef unsigned short u16;
typedef short bf16x8 __attribute__((ext_vector_type(8)));
typedef float f32x4 __attribute__((ext_vector_type(4)));
typedef u16 u16x4 __attribute__((ext_vector_type(4)));

#define DEVFN static __device__ __forceinline__

constexpr int Bz = 2, Nn = 2048, Mm = 512, Cc = 1536, Hh = 12, HD = 128;
constexpr int Ss = Nn + Mm;                 // 2560
constexpr float EPSV = 1e-6f;
constexpr float SCL = 0.08838834764831845f; // 128^-0.5

DEVFN u16 f2bf(float f) {
  union { float f; unsigned u; } v; v.f = f;
  unsigned r = v.u + 0x7fffu + ((v.u >> 16) & 1u);
  return (u16)(r >> 16);
}

DEVFN unsigned cvtpk(float lo, float hi) {
  unsigned r;
  asm("v_cvt_pk_bf16_f32 %0, %1, %2" : "=v"(r) : "v"(lo), "v"(hi));
  return r;
}

DEVFN void gload16(const void* g, void* l) {
  __builtin_amdgcn_global_load_lds((const __attribute__((address_space(1))) void*)g,
                                   (__attribute__((address_space(3))) void*)l, 16, 0, 0);
}

DEVFN f32x4 mfma16(bf16x8 a, bf16x8 b, f32x4 c) {
  return __builtin_amdgcn_mfma_f32_16x16x32_bf16(a, b, c, 0, 0, 0);
}

// XCD-chunked block swizzle (requires nwg % 8 == 0)
DEVFN int xcdswz(int hw, int nwg) {
  int q = nwg >> 3;
  return (hw & 7) * q + (hw >> 3);
}

// ---------------- prep kernels ----------------

__global__ void k_convert(const float* __restrict__ in, u16* __restrict__ out, int n) {
  int i = (blockIdx.x * blockDim.x + threadIdx.x) * 4;
  if (i < n) {
    float4 v = *(const float4*)(in + i);
    u16x4 o = { f2bf(v.x), f2bf(v.y), f2bf(v.z), f2bf(v.w) };
    *(u16x4*)(out + i) = o;
  }
}

// in: f32 (R x Ccols) row-major -> out: bf16 (Ccols x R)
__global__ void k_transpose_conv(const float* __restrict__ in, u16* __restrict__ out,
                                 int R, int Ccols) {
  __shared__ float t[32][33];
  int c0 = blockIdx.x * 32, r0 = blockIdx.y * 32;
  int lr = threadIdx.x >> 5, lc = threadIdx.x & 31;
#pragma unroll
  for (int i = 0; i < 4; ++i)
    t[lr + 8 * i][lc] = in[(long)(r0 + lr + 8 * i) * Ccols + c0 + lc];
  __syncthreads();
#pragma unroll
  for (int i = 0; i < 4; ++i)
    out[(long)(c0 + lr + 8 * i) * R + r0 + lc] = f2bf(t[lc][lr + 8 * i]);
}

__global__ void k_bias(const float* __restrict__ w, float* __restrict__ bias) {
  int i = blockIdx.x * 256 + threadIdx.x;
  if (i < Bz * Ss) {
    int b = i / Ss, s = i % Ss;
    bias[i] = (s < Nn) ? 0.0f : logf(fmaxf(w[b * Mm + s - Nn], 1e-4f));
  }
}

// ---------------- GEMM (A row-major MxK bf16, Bt = B^T (N x K) bf16) ----------------
// Single-buffer BK=64; L2-capacity-aware supertile swizzle: each XCD walks
// stbx x stby block supertiles (A-slice + B-slice fit its private 4MB L2).
// MODE 0: plain + bproj -> f32 out
// MODE 1: qkv epilogue  (s=0 q: RMS+RoPE+SCL, s=1 kx: RMS+RoPE, s=2 vx -> transposed)
// MODE 2: kv  epilogue  (s=0 ky: RMS only -> k[N..], s=1 vy -> transposed v[N..])
template <int MODE>
__global__ __launch_bounds__(256, MODE == 0 ? 4 : 3) void k_gemm(
    const u16* __restrict__ A, const u16* __restrict__ Bt,
    int K, int NC, int rowsPerB, int stbx, int stby,
    const float* __restrict__ pos, const float* __restrict__ qnw,
    const float* __restrict__ knw, const float* __restrict__ bprj,
    u16* __restrict__ qout, u16* __restrict__ kout, u16* __restrict__ vout,
    float* __restrict__ fout) {
  __shared__ __align__(16) u16 As[128 * 64];
  __shared__ __align__(16) u16 Bs[128 * 64];
  __shared__ float red[256];
  const int tid = threadIdx.x;
  const int lane = tid & 63;
  const int wid = tid >> 6;
  const int g = lane >> 4, cl = lane & 15;
  const int wr = wid >> 1, wc = wid & 1;

  // --- supertile swizzle (bijective; all grids sized for divisibility) ---
  const int gx = gridDim.x;
  const int nwg = gx * gridDim.y;
  const int hw = blockIdx.x + gx * blockIdx.y;
  const int xcd = hw & 7, j = hw >> 3;     // hw&7 == XCD (round-robin dispatch)
  const int stsz = stbx * stby;
  const int stpx = (nwg >> 3) / stsz;      // supertiles per XCD
  const int st = j / stsz, wi = j % stsz;
  const int gst = xcd * stpx + st;         // global supertile id
  const int nstx = gx / stbx;
  const int bx = (gst % nstx) * stbx + wi % stbx;
  const int by = (gst / nstx) * stby + wi / stbx;
  const long m0 = (long)bx * 128, n0 = (long)by * 128;

  f32x4 acc[4][4] = {};

  const int arow0 = tid >> 3;
  const int sxb = (((tid & 7) ^ (arow0 & 7)) << 4);
  const long K2 = (long)K * 2;
  const char* Abase = (const char*)A + (m0 + arow0) * K2 + sxb;
  const char* Bbase = (const char*)Bt + (n0 + arow0) * K2 + sxb;
  const int dtid = tid * 16;

  const int nt = K / 64;
  for (int kt = 0; kt < nt; ++kt) {
    __syncthreads();  // previous iteration's reads complete
    const long ko = (long)kt * 128;
#pragma unroll
    for (int i = 0; i < 4; ++i) {
      gload16(Abase + i * 32 * K2 + ko, (char*)As + i * 4096 + dtid);
      gload16(Bbase + i * 32 * K2 + ko, (char*)Bs + i * 4096 + dtid);
    }
    __syncthreads();  // staged data visible
    __builtin_amdgcn_s_setprio(1);
#pragma unroll
    for (int s = 0; s < 2; ++s) {
      bf16x8 af[4], bfr[4];
#pragma unroll
      for (int m = 0; m < 4; ++m) {
        int row = wr * 64 + m * 16 + cl;
        af[m] = *(const bf16x8*)((const char*)As + row * 128 + (((s * 4 + g) ^ (row & 7)) << 4));
      }
#pragma unroll
      for (int n = 0; n < 4; ++n) {
        int row = wc * 64 + n * 16 + cl;
        bfr[n] = *(const bf16x8*)((const char*)Bs + row * 128 + (((s * 4 + g) ^ (row & 7)) << 4));
      }
#pragma unroll
      for (int m = 0; m < 4; ++m)
#pragma unroll
        for (int n = 0; n < 4; ++n)
          acc[m][n] = mfma16(af[m], bfr[n], acc[m][n]);
    }
    __builtin_amdgcn_s_setprio(0);
  }

  if (MODE == 0) {
#pragma unroll
    for (int n = 0; n < 4; ++n) {
      int col = (int)n0 + wc * 64 + n * 16 + cl;
      float bv = bprj[col];
#pragma unroll
      for (int m = 0; m < 4; ++m)
#pragma unroll
        for (int r = 0; r < 4; ++r) {
          long row = m0 + wr * 64 + m * 16 + 4 * g + r;
          fout[row * NC + col] = acc[m][n][r] + bv;
        }
    }
    return;
  }

  // ---- fused epilogues ----
  const int ct = by;
  const int s_idx = ct / Hh, h = ct % Hh;
  const int bb = (int)(m0 / rowsPerB);
  const int bh = bb * Hh + h;
  const int seq0 = (int)(m0 % rowsPerB) + wr * 64;
  const bool is_v = (MODE == 1) ? (s_idx == 2) : (s_idx == 1);
  const bool do_norm = !is_v;
  const bool do_rope = (MODE == 1) && (s_idx < 2);

  if (is_v) {
    const long s0 = (MODE == 2 ? Nn : 0) + seq0;
#pragma unroll
    for (int m = 0; m < 4; ++m) {
      long sb = s0 + m * 16 + 4 * g;
#pragma unroll
      for (int n = 0; n < 4; ++n) {
        int d = wc * 64 + n * 16 + cl;
        u16x4 pk = { f2bf(acc[m][n][0]), f2bf(acc[m][n][1]),
                     f2bf(acc[m][n][2]), f2bf(acc[m][n][3]) };
        *(u16x4*)(vout + ((long)bh * HD + d) * Ss + sb) = pk;
      }
    }
    return;
  }

  if (do_norm) {
    float rs[4][4];
#pragma unroll
    for (int m = 0; m < 4; ++m)
#pragma unroll
      for (int r = 0; r < 4; ++r) {
        float t = 0.f;
#pragma unroll
        for (int n = 0; n < 4; ++n) t += acc[m][n][r] * acc[m][n][r];
        t += __shfl_xor(t, 1);
        t += __shfl_xor(t, 2);
        t += __shfl_xor(t, 4);
        t += __shfl_xor(t, 8);
        if (cl == 0) red[wc * 128 + wr * 64 + m * 16 + 4 * g + r] = t;
      }
    __syncthreads();
#pragma unroll
    for (int m = 0; m < 4; ++m)
#pragma unroll
      for (int r = 0; r < 4; ++r) {
        int row = wr * 64 + m * 16 + 4 * g + r;
        rs[m][r] = rsqrtf((red[row] + red[128 + row]) * (1.0f / 128.0f) + EPSV);
      }
    const float* nw = (MODE == 1 && s_idx == 0) ? qnw : knw;
    const float nsc = (MODE == 1 && s_idx == 0) ? SCL : 1.0f;
#pragma unroll
    for (int n = 0; n < 4; ++n) {
      float nwv = nw[wc * 64 + n * 16 + cl] * nsc;
#pragma unroll
      for (int m = 0; m < 4; ++m)
#pragma unroll
        for (int r = 0; r < 4; ++r) acc[m][n][r] *= rs[m][r] * nwv;
    }
  }

  if (do_rope && wc == 0) {
#pragma unroll
    for (int m = 0; m < 4; ++m)
#pragma unroll
      for (int r = 0; r < 4; ++r) {
        int seq = seq0 + m * 16 + 4 * g + r;
#pragma unroll
        for (int n = 0; n < 2; ++n) {
          int d = n * 16 + cl;  // 0..31
          float cs = pos[(seq * 32 + d) * 2 + 0];
          float sn = pos[(seq * 32 + d) * 2 + 1];
          float t1 = acc[m][n][r], t2 = acc[m][n + 2][r];
          acc[m][n][r] = t1 * cs - t2 * sn;
          acc[m][n + 2][r] = t1 * sn + t2 * cs;
        }
      }
  }

  u16* ob;
  long sbase;
  if (MODE == 1) {
    if (s_idx == 0) { ob = qout; sbase = (long)bh * Nn; }
    else { ob = kout; sbase = (long)bh * Ss; }
  } else {
    ob = kout;
    sbase = (long)bh * Ss + Nn;
  }
#pragma unroll
  for (int m = 0; m < 4; ++m)
#pragma unroll
    for (int r = 0; r < 4; ++r) {
      long rowb = (sbase + seq0 + m * 16 + 4 * g + r) * HD;
#pragma unroll
      for (int n = 0; n < 4; ++n)
        ob[rowb + wc * 64 + n * 16 + cl] = f2bf(acc[m][n][r]);
    }
}

// ---------------- flash attention (pipelined LDS staging, swapped QK) ----------------
// Q (BH,Nn,HD) bf16 (pre-scaled by SCL), K (BH,Ss,HD), Vt (BH,HD,Ss), bias (Bz,Ss) f32
// 128 q/block, 4 waves x 32 q (m=2). KV tile 64, double-buffered, 1 barrier/tile.
// XCD swizzle: all 16 q-tiles of a head on one XCD (KV L2-resident).
__global__ __launch_bounds__(256, 2) void k_flash(
    const u16* __restrict__ Q, const u16* __restrict__ K, const u16* __restrict__ Vt,
    const float* __restrict__ bias, u16* __restrict__ Aout) {
  __shared__ __align__(16) u16 Ks[2][64 * 128];
  __shared__ __align__(16) u16 Vs[2][128 * 64];
  __shared__ __align__(16) u16 Ps[4][16 * 64];
  const int tid = threadIdx.x, lane = tid & 63, wid = tid >> 6;
  const int g = lane >> 4, cl = lane & 15;
  const int hw = blockIdx.x + gridDim.x * blockIdx.y;
  const int wg = xcdswz(hw, gridDim.x * gridDim.y);
  const int qt = wg % gridDim.x, bh = wg / gridDim.x;
  const int b = bh / Hh, h = bh % Hh;
  const int n0 = qt * 128;
  constexpr int NT = Ss / 64;  // 40

  const u16* Qg = Q + ((long)bh * Nn + n0 + wid * 32) * HD;
  const char* Kg = (const char*)(K + (long)bh * Ss * HD);
  const char* Vg = (const char*)(Vt + (long)bh * HD * Ss);
  const float* bg = bias + b * Ss;

  bf16x8 qf[2][4];
#pragma unroll
  for (int m = 0; m < 2; ++m)
#pragma unroll
    for (int kk = 0; kk < 4; ++kk)
      qf[m][kk] = *(const bf16x8*)(Qg + (m * 16 + cl) * HD + kk * 32 + g * 8);

  const int krow = tid >> 4;
  const char* Ksrc = Kg + krow * 256 + (((tid & 15) ^ (krow & 7)) << 4);
  const int vrow = tid >> 3;
  const char* Vsrc = Vg + (long)vrow * (Ss * 2) + (((tid & 7) ^ (vrow & 7)) << 4);
  const int dsto = (tid & ~63) << 4;

  auto STAGE = [&](int t, int s) {
    char* kd = (char*)Ks[s] + dsto;
    char* vd = (char*)Vs[s] + dsto;
    long kb = (long)t * 64;
#pragma unroll
    for (int i = 0; i < 4; ++i) gload16(Ksrc + kb * 256 + i * (16 * 256), kd + i * 4096);
#pragma unroll
    for (int i = 0; i < 4; ++i) gload16(Vsrc + kb * 2 + (long)i * 32 * (Ss * 2), vd + i * 4096);
  };

  f32x4 ov[2][8] = {};
  float mi[2] = {-3e38f, -3e38f}, li[2] = {0.f, 0.f};
  u16* pt = (u16*)Ps[wid];
  const int h7 = (cl & 7) << 1;

  STAGE(0, 0);
  __syncthreads();
  int cur = 0;
  for (int t = 0; t < NT; ++t) {
    if (t + 1 < NT) STAGE(t + 1, cur ^ 1);
    const bool biased = (t * 64 >= Nn);
    float badd[4][4];
    if (biased) {
#pragma unroll
      for (int n = 0; n < 4; ++n)
#pragma unroll
        for (int r = 0; r < 4; ++r)
          badd[n][r] = bg[t * 64 + n * 16 + 4 * g + r];
    }
    const char* ks = (const char*)Ks[cur];
    const char* vs = (const char*)Vs[cur];

    // S^T = K Q^T : lane holds kv = n*16+4g+r (regs), q = m*16+cl
    f32x4 sc[2][4] = {};
    __builtin_amdgcn_s_setprio(1);
#pragma unroll
    for (int n = 0; n < 4; ++n) {
      int krw = n * 16 + cl;
#pragma unroll
      for (int kk = 0; kk < 4; ++kk) {
        bf16x8 kf = *(const bf16x8*)(ks + krw * 256 + (((kk * 4 + g) ^ (krw & 7)) << 4));
        sc[0][n] = mfma16(kf, qf[0][kk], sc[0][n]);
        sc[1][n] = mfma16(kf, qf[1][kk], sc[1][n]);
      }
    }
    __builtin_amdgcn_s_setprio(0);

    // online softmax with deferred rescale (T13, THR=8)
    float pmax[2];
#pragma unroll
    for (int m = 0; m < 2; ++m) {
      float mx = -3e38f;
#pragma unroll
      for (int n = 0; n < 4; ++n)
#pragma unroll
        for (int r = 0; r < 4; ++r) {
          float s = sc[m][n][r];
          if (biased) s += badd[n][r];
          sc[m][n][r] = s;
          mx = fmaxf(mx, s);
        }
      mx = fmaxf(mx, __shfl_xor(mx, 16));
      mx = fmaxf(mx, __shfl_xor(mx, 32));
      pmax[m] = mx;
    }
    if (__any((pmax[0] > mi[0] + 8.f) || (pmax[1] > mi[1] + 8.f))) {
      float co_s[2];
#pragma unroll
      for (int m = 0; m < 2; ++m) {
        float mnew = fmaxf(mi[m], pmax[m]);
        co_s[m] = __expf(mi[m] - mnew);
        mi[m] = mnew;
        li[m] *= co_s[m];
      }
#pragma unroll
      for (int m = 0; m < 2; ++m)
#pragma unroll
        for (int r = 0; r < 4; ++r) {
          float cr = __shfl(co_s[m], 4 * g + r, 64);
#pragma unroll
          for (int nd = 0; nd < 8; ++nd) ov[m][nd][r] *= cr;
        }
    }
#pragma unroll
    for (int m = 0; m < 2; ++m) {
      float rsum = 0.f;
#pragma unroll
      for (int n = 0; n < 4; ++n)
#pragma unroll
        for (int r = 0; r < 4; ++r) {
          float p = __expf(sc[m][n][r] - mi[m]);
          sc[m][n][r] = p;
          rsum += p;
        }
      rsum += __shfl_xor(rsum, 16);
      rsum += __shfl_xor(rsum, 32);
      li[m] += rsum;
    }

    // P[q][kv] via packed b64 writes (XOR-swizzled), read back as b128 A-frags
    bf16x8 pf[2][2];
#pragma unroll
    for (int m = 0; m < 2; ++m) {
#pragma unroll
      for (int n = 0; n < 4; ++n) {
        uint2 w;
        w.x = cvtpk(sc[m][n][0], sc[m][n][1]);
        w.y = cvtpk(sc[m][n][2], sc[m][n][3]);
        *(uint2*)((char*)pt + cl * 128 + (((4 * n + g) ^ h7) << 3)) = w;
      }
#pragma unroll
      for (int ks2 = 0; ks2 < 2; ++ks2)
        pf[m][ks2] = *(const bf16x8*)((const char*)pt + cl * 128 +
                                      (((8 * ks2 + 2 * g) ^ h7) << 3));
    }

    // O += P V
    __builtin_amdgcn_s_setprio(1);
#pragma unroll
    for (int nd = 0; nd < 8; ++nd) {
      int vrw = nd * 16 + cl;
#pragma unroll
      for (int ks2 = 0; ks2 < 2; ++ks2) {
        bf16x8 vf = *(const bf16x8*)(vs + vrw * 128 + (((ks2 * 4 + g) ^ (vrw & 7)) << 4));
        ov[0][nd] = mfma16(pf[0][ks2], vf, ov[0][nd]);
        ov[1][nd] = mfma16(pf[1][ks2], vf, ov[1][nd]);
      }
    }
    __builtin_amdgcn_s_setprio(0);
    __syncthreads();
    cur ^= 1;
  }

#pragma unroll
  for (int m = 0; m < 2; ++m) {
    float inv = 1.0f / li[m];
#pragma unroll
    for (int r = 0; r < 4; ++r) {
      float iv = __shfl(inv, 4 * g + r, 64);
      long row = (long)b * Nn + n0 + wid * 32 + m * 16 + 4 * g + r;
      long base = row * Cc + h * HD;
#pragma unroll
      for (int nd = 0; nd < 8; ++nd)
        Aout[base + nd * 16 + cl] = f2bf(ov[m][nd][r] * iv);
    }
  }
}

// ---------------- launcher ----------------

extern "C" void kernel_launch(void* const* d_in, const int* in_sizes, int n_in,
                              void* d_out, int out_size, void* d_ws, size_t ws_size,
                              hipStream_t stream) {
  const float* x = (const float*)d_in[0];
  const float* y = (const float*)d_in[1];
  const float* pos = (const float*)d_in[2];
  const float* ytw = (const float*)d_in[3];
  const float* Wqkv = (const float*)d_in[4];
  const float* Wkv = (const float*)d_in[5];
  const float* qnw = (const float*)d_in[6];
  const float* knw = (const float*)d_in[7];
  const float* Wproj = (const float*)d_in[8];
  const float* bproj = (const float*)d_in[9];
  float* out = (float*)d_out;
  char* ws = (char*)d_ws;

  size_t o = 0;
  auto take = [&](size_t b) {
    char* p = ws + o;
    o += (b + 255) & ~(size_t)255;
    return p;
  };
  u16* xb = (u16*)take((size_t)Bz * Nn * Cc * 2);
  u16* yb = (u16*)take((size_t)Bz * Mm * Cc * 2);
  u16* wqkvt = (u16*)take((size_t)3 * Cc * Cc * 2);
  u16* wkvt = (u16*)take((size_t)2 * Cc * Cc * 2);
  u16* wprjt = (u16*)take((size_t)Cc * Cc * 2);
  u16* qb = (u16*)take((size_t)Bz * Hh * Nn * HD * 2);
  u16* kb = (u16*)take((size_t)Bz * Hh * Ss * HD * 2);
  u16* vtb = (u16*)take((size_t)Bz * Hh * Ss * HD * 2);
  u16* ab = (u16*)take((size_t)Bz * Nn * Cc * 2);
  float* bias = (float*)take((size_t)Bz * Ss * 4);

  k_convert<<<dim3(Bz * Nn * Cc / 1024), 256, 0, stream>>>(x, xb, Bz * Nn * Cc);
  k_convert<<<dim3(Bz * Mm * Cc / 1024), 256, 0, stream>>>(y, yb, Bz * Mm * Cc);
  k_transpose_conv<<<dim3(3 * Cc / 32, Cc / 32), 256, 0, stream>>>(Wqkv, wqkvt, Cc, 3 * Cc);
  k_transpose_conv<<<dim3(2 * Cc / 32, Cc / 32), 256, 0, stream>>>(Wkv, wkvt, Cc, 2 * Cc);
  k_transpose_conv<<<dim3(Cc / 32, Cc / 32), 256, 0, stream>>>(Wproj, wprjt, Cc, Cc);
  k_bias<<<dim3((Bz * Ss + 255) / 256), 256, 0, stream>>>(ytw, bias);
  // g1: grid (32,36) -> supertile 4x4 (A 1.6MB + B 1.6MB per XCD L2)
  k_gemm<1><<<dim3(Bz * Nn / 128, 3 * Cc / 128), 256, 0, stream>>>(
      xb, wqkvt, Cc, 3 * Cc, Nn, 4, 4, pos, qnw, knw, nullptr, qb, kb, vtb, nullptr);
  // g2: grid (8,24) -> supertile 2x4
  k_gemm<2><<<dim3(Bz * Mm / 128, 2 * Cc / 128), 256, 0, stream>>>(
      yb, wkvt, Cc, 2 * Cc, Mm, 2, 4, pos, qnw, knw, nullptr, nullptr, kb, vtb, nullptr);
  k_flash<<<dim3(Nn / 128, Bz * Hh), 256, 0, stream>>>(qb, kb, vtb, bias, ab);
  // g0: grid (32,12) -> supertile 4x4
  k_gemm<0><<<dim3(Bz * Nn / 128, Cc / 128), 256, 0, stream>>>(
      ab, wprjt, Cc, Cc, Nn, 4, 4, nullptr, nullptr, nullptr, bproj, nullptr, nullptr, nullptr, out);
}